// Round 1
// baseline (2057.820 us; speedup 1.0000x reference)
//
#include <hip/hip_runtime.h>
#include <hip/hip_bf16.h>

#define S_LEN 1024
#define BATCH 16
#define QD 128
#define NH 8
#define HD 32
#define FF 512
#define NROWS (BATCH * S_LEN)  // 16384 token rows
#define EPS 1e-5f

__device__ __forceinline__ float wave_reduce_sum(float v) {
#pragma unroll
    for (int m = 1; m < 64; m <<= 1) v += __shfl_xor(v, m, 64);
    return v;
}
__device__ __forceinline__ float wave_reduce_max(float v) {
#pragma unroll
    for (int m = 1; m < 64; m <<= 1) v = fmaxf(v, __shfl_xor(v, m, 64));
    return v;
}

// ---------------------------------------------------------------------------
// Kernel 1: fused Q/K/V projection.
// grid 2048 blocks (8 token-rows each), block 256 threads = (h, d) pairs.
// q/k/v layout: [(b*8+h)*1024 + s][32]
// ---------------------------------------------------------------------------
__global__ __launch_bounds__(256) void qkv_proj(
    const float* __restrict__ seq,
    const float* __restrict__ Wq, const float* __restrict__ bq,
    const float* __restrict__ Wk, const float* __restrict__ bk,
    const float* __restrict__ Wv, const float* __restrict__ bv,
    float* __restrict__ q, float* __restrict__ k, float* __restrict__ v) {
    __shared__ float xs[8][QD];
    const int r0 = blockIdx.x * 8;
    const int tid = threadIdx.x;
    for (int e = tid; e < 8 * QD; e += 256) {
        int r = e >> 7, c = e & 127;
        int g = r0 + r;
        int b = g >> 10, s = g & 1023;
        xs[r][c] = seq[(s * BATCH + b) * QD + c];
    }
    __syncthreads();
    const int h = tid >> 5, d = tid & 31;
    float aq[8], ak[8], av[8];
#pragma unroll
    for (int r = 0; r < 8; ++r) { aq[r] = 0.f; ak[r] = 0.f; av[r] = 0.f; }
    const float* wq = Wq + h * QD * HD + d;
    const float* wk = Wk + h * QD * HD + d;
    const float* wv = Wv + h * QD * HD + d;
    for (int c = 0; c < QD; ++c) {
        float wqv = wq[c * HD], wkv = wk[c * HD], wvv = wv[c * HD];
#pragma unroll
        for (int r = 0; r < 8; ++r) {
            float x = xs[r][c];
            aq[r] += x * wqv;
            ak[r] += x * wkv;
            av[r] += x * wvv;
        }
    }
    const float bqv = bq[h * HD + d], bkv = bk[h * HD + d], bvv = bv[h * HD + d];
#pragma unroll
    for (int r = 0; r < 8; ++r) {
        int g = r0 + r;
        int b = g >> 10, s = g & 1023;
        int off = ((b * NH + h) * S_LEN + s) * HD + d;
        q[off] = aq[r] + bqv;
        k[off] = ak[r] + bkv;
        v[off] = av[r] + bvv;
    }
}

// ---------------------------------------------------------------------------
// Kernel 2: attention. One wave per query row; 4 rows per block share staged
// K/V chunks in LDS. Scores kept in registers (16/lane), two-pass softmax.
// o layout: [b*S + s][256] (heads concatenated)
// ---------------------------------------------------------------------------
__global__ __launch_bounds__(256) void attn_kernel(
    const float* __restrict__ q, const float* __restrict__ k,
    const float* __restrict__ v, float* __restrict__ o) {
    __shared__ float smem[4 * 64 * 33];  // red[4][64][33]; K at 0, V at 64*33
    const int tid = threadIdx.x;
    const int w = tid >> 6, lane = tid & 63;
    const int row = blockIdx.x * 4 + w;  // ((b*8+h)*1024 + s)
    const int bh = row >> 10;
    const int s = row & 1023;
    const float* Kb = k + (size_t)bh * S_LEN * HD;
    const float* Vb = v + (size_t)bh * S_LEN * HD;

    float qr[HD];
    {
        const float* qp = q + (size_t)row * HD;
#pragma unroll
        for (int d = 0; d < HD; ++d) qr[d] = qp[d];
    }

    float* Ks = smem;            // [64][33]
    float* Vs = smem + 64 * 33;  // [64][33]
    float sc[16];

    // pass 1: scores
    for (int i = 0; i < 16; ++i) {
        __syncthreads();
        for (int e = tid; e < 64 * HD; e += 256) {
            int t = e >> 5, d = e & 31;
            Ks[t * 33 + d] = Kb[(i * 64 + t) * HD + d];
        }
        __syncthreads();
        float acc = 0.f;
#pragma unroll
        for (int d = 0; d < HD; ++d) acc += qr[d] * Ks[lane * 33 + d];
        sc[i] = acc * 0.17677669529663687f;  // 1/sqrt(32)
    }

    // softmax over the row (in registers)
    float m = -1e30f;
#pragma unroll
    for (int i = 0; i < 16; ++i) m = fmaxf(m, sc[i]);
    m = wave_reduce_max(m);
    float l = 0.f;
#pragma unroll
    for (int i = 0; i < 16; ++i) {
        sc[i] = __expf(sc[i] - m);
        l += sc[i];
    }
    l = wave_reduce_sum(l);
    const float inv_l = 1.0f / l;

    // pass 2: P·V
    float acc[HD];
#pragma unroll
    for (int d = 0; d < HD; ++d) acc[d] = 0.f;
    for (int i = 0; i < 16; ++i) {
        __syncthreads();
        for (int e = tid; e < 64 * HD; e += 256) {
            int t = e >> 5, d = e & 31;
            Vs[t * 33 + d] = Vb[(i * 64 + t) * HD + d];
        }
        __syncthreads();
        float p = sc[i];
#pragma unroll
        for (int d = 0; d < HD; ++d) acc[d] += p * Vs[lane * 33 + d];
    }

    // cross-lane reduce via LDS (conflict-free: stride 33)
    __syncthreads();
    float* red = smem;  // [4][64][33]
#pragma unroll
    for (int d = 0; d < HD; ++d) red[(w * 64 + lane) * 33 + d] = acc[d];
    __syncthreads();
    if (lane < HD) {
        float sum = 0.f;
#pragma unroll
        for (int l2 = 0; l2 < 64; ++l2) sum += red[(w * 64 + l2) * 33 + lane];
        int b = bh >> 3, h = bh & 7;
        o[((size_t)(b * S_LEN + s)) * (NH * HD) + h * HD + lane] = sum * inv_l;
    }
}

// ---------------------------------------------------------------------------
// Kernel 3: att_outs = LN(x + o @ Wo + bo). Block = 128 threads, 8 rows.
// ---------------------------------------------------------------------------
__global__ __launch_bounds__(128) void wo_ln(
    const float* __restrict__ o, const float* __restrict__ Wo,
    const float* __restrict__ bo, const float* __restrict__ seq,
    const float* __restrict__ gamma, const float* __restrict__ beta,
    float* __restrict__ att) {
    __shared__ float os[8][NH * HD];
    __shared__ float rs1[2][8], rs2[2][8];
    const int r0 = blockIdx.x * 8;
    const int tid = threadIdx.x;
    const int c = tid;
    for (int e = tid; e < 8 * NH * HD; e += 128) {
        int r = e >> 8, j = e & 255;
        os[r][j] = o[(size_t)(r0 + r) * (NH * HD) + j];
    }
    __syncthreads();
    float acc[8];
#pragma unroll
    for (int r = 0; r < 8; ++r) acc[r] = 0.f;
    for (int j = 0; j < NH * HD; ++j) {
        float wv = Wo[j * QD + c];
#pragma unroll
        for (int r = 0; r < 8; ++r) acc[r] += os[r][j] * wv;
    }
    const float bv = bo[c];
#pragma unroll
    for (int r = 0; r < 8; ++r) {
        int g = r0 + r;
        int b = g >> 10, s = g & 1023;
        acc[r] += bv + seq[(s * BATCH + b) * QD + c];
    }
    // layernorm across 128 channels (2 waves)
    const int w = tid >> 6, lane = tid & 63;
#pragma unroll
    for (int r = 0; r < 8; ++r) {
        float s1 = wave_reduce_sum(acc[r]);
        float s2 = wave_reduce_sum(acc[r] * acc[r]);
        if (lane == 0) { rs1[w][r] = s1; rs2[w][r] = s2; }
    }
    __syncthreads();
    const float gm = gamma[c], bt = beta[c];
#pragma unroll
    for (int r = 0; r < 8; ++r) {
        float S1 = rs1[0][r] + rs1[1][r];
        float S2 = rs2[0][r] + rs2[1][r];
        float mu = S1 * (1.0f / QD);
        float var = S2 * (1.0f / QD) - mu * mu;
        float rstd = rsqrtf(var + EPS);
        att[(size_t)(r0 + r) * QD + c] = (acc[r] - mu) * rstd * gm + bt;
    }
}

// ---------------------------------------------------------------------------
// Kernel 4/5: FFN GEMM with ReLU. out[g][f] = relu(A[g][:] @ W + bias[f])
// block 128 threads (one column each), 8 rows per block, grid.y = col tiles.
// ---------------------------------------------------------------------------
template <int K>
__global__ __launch_bounds__(128) void ffn_gemm(
    const float* __restrict__ A, const float* __restrict__ W,
    const float* __restrict__ bias, float* __restrict__ out, int N) {
    __shared__ float as[8][128];
    const int r0 = blockIdx.x * 8;
    const int tid = threadIdx.x;
    const int f = blockIdx.y * 128 + tid;
    float acc[8];
#pragma unroll
    for (int r = 0; r < 8; ++r) acc[r] = 0.f;
    for (int kc = 0; kc < K; kc += 128) {
        __syncthreads();
#pragma unroll
        for (int r = 0; r < 8; ++r) as[r][tid] = A[(size_t)(r0 + r) * K + kc + tid];
        __syncthreads();
        for (int j = 0; j < 128; ++j) {
            float wv = W[(size_t)(kc + j) * N + f];
#pragma unroll
            for (int r = 0; r < 8; ++r) acc[r] += as[r][j] * wv;
        }
    }
    const float bv = bias[f];
#pragma unroll
    for (int r = 0; r < 8; ++r) {
        float x = acc[r] + bv;
        out[(size_t)(r0 + r) * N + f] = fmaxf(x, 0.f);
    }
}

// ---------------------------------------------------------------------------
// Kernel 6: out = LN(att + h2 @ W3 + b3), written transposed to [S, B, 128].
// ---------------------------------------------------------------------------
__global__ __launch_bounds__(128) void w3_ln_out(
    const float* __restrict__ h2, const float* __restrict__ W3,
    const float* __restrict__ b3, const float* __restrict__ att,
    const float* __restrict__ gamma, const float* __restrict__ beta,
    float* __restrict__ out) {
    __shared__ float hs[8][FF];
    __shared__ float rs1[2][8], rs2[2][8];
    const int r0 = blockIdx.x * 8;
    const int tid = threadIdx.x;
    const int c = tid;
    for (int e = tid; e < 8 * FF; e += 128) {
        int r = e >> 9, j = e & 511;
        hs[r][j] = h2[(size_t)(r0 + r) * FF + j];
    }
    __syncthreads();
    float acc[8];
#pragma unroll
    for (int r = 0; r < 8; ++r) acc[r] = 0.f;
    for (int j = 0; j < FF; ++j) {
        float wv = W3[j * QD + c];
#pragma unroll
        for (int r = 0; r < 8; ++r) acc[r] += hs[r][j] * wv;
    }
    const float bv = b3[c];
#pragma unroll
    for (int r = 0; r < 8; ++r)
        acc[r] += bv + att[(size_t)(r0 + r) * QD + c];
    const int w = tid >> 6, lane = tid & 63;
#pragma unroll
    for (int r = 0; r < 8; ++r) {
        float s1 = wave_reduce_sum(acc[r]);
        float s2 = wave_reduce_sum(acc[r] * acc[r]);
        if (lane == 0) { rs1[w][r] = s1; rs2[w][r] = s2; }
    }
    __syncthreads();
    const float gm = gamma[c], bt = beta[c];
#pragma unroll
    for (int r = 0; r < 8; ++r) {
        float S1 = rs1[0][r] + rs1[1][r];
        float S2 = rs2[0][r] + rs2[1][r];
        float mu = S1 * (1.0f / QD);
        float var = S2 * (1.0f / QD) - mu * mu;
        float rstd = rsqrtf(var + EPS);
        int g = r0 + r;
        int b = g >> 10, s = g & 1023;
        out[(size_t)(s * BATCH + b) * QD + c] = (acc[r] - mu) * rstd * gm + bt;
    }
}

extern "C" void kernel_launch(void* const* d_in, const int* in_sizes, int n_in,
                              void* d_out, int out_size, void* d_ws, size_t ws_size,
                              hipStream_t stream) {
    const float* seq = (const float*)d_in[0];
    const float* Wq = (const float*)d_in[1];
    const float* bq = (const float*)d_in[2];
    const float* Wk = (const float*)d_in[3];
    const float* bk = (const float*)d_in[4];
    const float* Wv = (const float*)d_in[5];
    const float* bv = (const float*)d_in[6];
    const float* Wo = (const float*)d_in[7];
    const float* bo = (const float*)d_in[8];
    const float* gamma = (const float*)d_in[9];
    const float* beta = (const float*)d_in[10];
    const float* W1 = (const float*)d_in[11];
    const float* b1 = (const float*)d_in[12];
    const float* W2 = (const float*)d_in[13];
    const float* b2 = (const float*)d_in[14];
    const float* W3 = (const float*)d_in[15];
    const float* b3 = (const float*)d_in[16];

    float* ws = (float*)d_ws;
    float* q = ws;                      // 4 Mi floats
    float* k = ws + 4194304;            // 4 Mi
    float* v = ws + 8388608;            // 4 Mi
    float* o = ws + 12582912;           // 4 Mi
    float* att = ws + 16777216;         // 2 Mi
    float* h1 = ws;                     // reuses q+k (8 Mi floats)
    float* h2 = ws + 8388608;           // reuses v+o (8 Mi floats)
    float* out = (float*)d_out;

    qkv_proj<<<NROWS / 8, 256, 0, stream>>>(seq, Wq, bq, Wk, bk, Wv, bv, q, k, v);
    attn_kernel<<<(BATCH * NH * S_LEN) / 4, 256, 0, stream>>>(q, k, v, o);
    wo_ln<<<NROWS / 8, 128, 0, stream>>>(o, Wo, bo, seq, gamma, beta, att);
    ffn_gemm<QD><<<dim3(NROWS / 8, FF / 128), 128, 0, stream>>>(att, W1, b1, h1, FF);
    ffn_gemm<FF><<<dim3(NROWS / 8, FF / 128), 128, 0, stream>>>(h1, W2, b2, h2, FF);
    w3_ln_out<<<NROWS / 8, 128, 0, stream>>>(h2, W3, b3, att, gamma, beta, out);
}

// Round 2
// 742.457 us; speedup vs baseline: 2.7716x; 2.7716x over previous
//
#include <hip/hip_runtime.h>
#include <hip/hip_bf16.h>

#define S_LEN 1024
#define BATCH 16
#define QD 128
#define NH 8
#define HD 32
#define FF 512
#define NROWS (BATCH * S_LEN)  // 16384 token rows
#define EPS 1e-5f

typedef __attribute__((ext_vector_type(4))) float f32x4;
typedef __attribute__((ext_vector_type(8))) short s16x8;
typedef __attribute__((ext_vector_type(4))) short s16x4;

__device__ __forceinline__ float wave_reduce_sum(float v) {
#pragma unroll
    for (int m = 1; m < 64; m <<= 1) v += __shfl_xor(v, m, 64);
    return v;
}

__device__ __forceinline__ ushort f2bfu(float f) {
    union { float f; unsigned u; } v; v.f = f;
    unsigned r = (v.u + 0x7FFFu + ((v.u >> 16) & 1u)) >> 16;  // RNE
    return (ushort)r;
}

static __device__ __forceinline__ f32x4 mfma16(s16x4 a, s16x4 b, f32x4 c) {
#if __has_builtin(__builtin_amdgcn_mfma_f32_16x16x16bf16_1k)
    return __builtin_amdgcn_mfma_f32_16x16x16bf16_1k(a, b, c, 0, 0, 0);
#else
    asm volatile("v_mfma_f32_16x16x16_bf16 %0, %1, %2, %0" : "+v"(c) : "v"(a), "v"(b));
    return c;
#endif
}

static __device__ __forceinline__ f32x4 mfma32(s16x8 a, s16x8 b, f32x4 c) {
    return __builtin_amdgcn_mfma_f32_16x16x32_bf16(a, b, c, 0, 0, 0);
}

// ---------------------------------------------------------------------------
// Kernel 1: fused Q/K/V projection -> bf16 outputs for MFMA attention.
// q_bf: [(b*8+h)*1024+s][32], pre-scaled by 1/sqrt(32)
// k_bf: [(b*8+h)*1024+s][32]
// vT  : [(b*8+h)*32+d][1024]   (transposed, for PV A-fragments)
// ---------------------------------------------------------------------------
__global__ __launch_bounds__(256) void qkv_proj(
    const float* __restrict__ seq,
    const float* __restrict__ Wq, const float* __restrict__ bq,
    const float* __restrict__ Wk, const float* __restrict__ bk,
    const float* __restrict__ Wv, const float* __restrict__ bv,
    ushort* __restrict__ q_bf, ushort* __restrict__ k_bf, ushort* __restrict__ vT) {
    __shared__ float xs[8][QD];
    const int r0 = blockIdx.x * 8;
    const int tid = threadIdx.x;
    for (int e = tid; e < 8 * QD; e += 256) {
        int r = e >> 7, c = e & 127;
        int g = r0 + r;
        int b = g >> 10, s = g & 1023;
        xs[r][c] = seq[(s * BATCH + b) * QD + c];
    }
    __syncthreads();
    const int h = tid >> 5, d = tid & 31;
    float aq[8], ak[8], av[8];
#pragma unroll
    for (int r = 0; r < 8; ++r) { aq[r] = 0.f; ak[r] = 0.f; av[r] = 0.f; }
    const float* wq = Wq + h * QD * HD + d;
    const float* wk = Wk + h * QD * HD + d;
    const float* wv = Wv + h * QD * HD + d;
    for (int c = 0; c < QD; ++c) {
        float wqv = wq[c * HD], wkv = wk[c * HD], wvv = wv[c * HD];
#pragma unroll
        for (int r = 0; r < 8; ++r) {
            float x = xs[r][c];
            aq[r] += x * wqv;
            ak[r] += x * wkv;
            av[r] += x * wvv;
        }
    }
    const float bqv = bq[h * HD + d], bkv = bk[h * HD + d], bvv = bv[h * HD + d];
    const float SCALE = 0.17677669529663687f;  // 1/sqrt(32)
    const int b = r0 >> 10, s0 = r0 & 1023;
    const int bh = b * NH + h;
    s16x8 pv;
#pragma unroll
    for (int r = 0; r < 8; ++r) {
        size_t idx = ((size_t)bh * S_LEN + (s0 + r)) * HD + d;
        q_bf[idx] = f2bfu((aq[r] + bqv) * SCALE);
        k_bf[idx] = f2bfu(ak[r] + bkv);
        pv[r] = (short)f2bfu(av[r] + bvv);
    }
    *(s16x8*)(vT + ((size_t)bh * HD + d) * S_LEN + s0) = pv;
}

// ---------------------------------------------------------------------------
// Kernel 2: flash-style MFMA attention. One wave per 16-query tile; no LDS.
// S^T = mfma_16x16x32(K_tile, Q_tile): lane holds S^T[4g+r][q=lane&15].
// O^T = V^T . P^T via mfma_16x16x16: S^T C-layout IS the B-fragment layout.
// o layout: [b*S+s][256] f32 (heads concatenated)
// ---------------------------------------------------------------------------
__global__ __launch_bounds__(256) void attn_mfma(
    const ushort* __restrict__ qb, const ushort* __restrict__ kb,
    const ushort* __restrict__ vtb, float* __restrict__ o) {
    const int tid = threadIdx.x;
    const int w = tid >> 6, lane = tid & 63;
    const int g = lane >> 4, qi = lane & 15;
    const int bh = blockIdx.x >> 4;
    const int qtile = (blockIdx.x & 15) * 4 + w;

    const ushort* Kb = kb + (size_t)bh * S_LEN * HD;
    const ushort* VTb = vtb + (size_t)bh * HD * S_LEN;

    // Q B-fragment: Q[qi][8g..8g+7], loaded once
    const s16x8 qf = *(const s16x8*)(qb + ((size_t)bh * S_LEN + qtile * 16 + qi) * HD + g * 8);

    f32x4 ot0 = {0.f, 0.f, 0.f, 0.f};
    f32x4 ot1 = {0.f, 0.f, 0.f, 0.f};
    float m_run = -1e30f, l_run = 0.f;
    const f32x4 zero = {0.f, 0.f, 0.f, 0.f};

#pragma unroll 2
    for (int it = 0; it < S_LEN / 32; ++it) {
        const int k0 = it * 32;
        // K A-fragments (rows k0+qi, k0+16+qi, cols 8g..8g+7)
        s16x8 ka0 = *(const s16x8*)(Kb + (size_t)(k0 + qi) * HD + g * 8);
        s16x8 ka1 = *(const s16x8*)(Kb + (size_t)(k0 + 16 + qi) * HD + g * 8);
        // V^T A-fragments: V^T[16h+qi][k0+16t+4g .. +3]
        s16x4 va00 = *(const s16x4*)(VTb + (size_t)qi * S_LEN + k0 + g * 4);
        s16x4 va01 = *(const s16x4*)(VTb + (size_t)(16 + qi) * S_LEN + k0 + g * 4);
        s16x4 va10 = *(const s16x4*)(VTb + (size_t)qi * S_LEN + k0 + 16 + g * 4);
        s16x4 va11 = *(const s16x4*)(VTb + (size_t)(16 + qi) * S_LEN + k0 + 16 + g * 4);

        f32x4 st0 = mfma32(ka0, qf, zero);  // keys k0+4g+r
        f32x4 st1 = mfma32(ka1, qf, zero);  // keys k0+16+4g+r

        // online softmax stats for this 32-key block (per q = lane&15)
        float mt = fmaxf(fmaxf(fmaxf(st0[0], st0[1]), fmaxf(st0[2], st0[3])),
                         fmaxf(fmaxf(st1[0], st1[1]), fmaxf(st1[2], st1[3])));
        mt = fmaxf(mt, __shfl_xor(mt, 16, 64));
        mt = fmaxf(mt, __shfl_xor(mt, 32, 64));
        const float m_new = fmaxf(m_run, mt);
        const float alpha = __expf(m_run - m_new);
        float p0 = __expf(st0[0] - m_new), p1 = __expf(st0[1] - m_new);
        float p2 = __expf(st0[2] - m_new), p3 = __expf(st0[3] - m_new);
        float p4 = __expf(st1[0] - m_new), p5 = __expf(st1[1] - m_new);
        float p6 = __expf(st1[2] - m_new), p7 = __expf(st1[3] - m_new);
        float lt = ((p0 + p1) + (p2 + p3)) + ((p4 + p5) + (p6 + p7));
        lt += __shfl_xor(lt, 16, 64);
        lt += __shfl_xor(lt, 32, 64);
        l_run = l_run * alpha + lt;
        m_run = m_new;
#pragma unroll
        for (int r = 0; r < 4; ++r) { ot0[r] *= alpha; ot1[r] *= alpha; }

        s16x4 pb0 = {(short)f2bfu(p0), (short)f2bfu(p1), (short)f2bfu(p2), (short)f2bfu(p3)};
        s16x4 pb1 = {(short)f2bfu(p4), (short)f2bfu(p5), (short)f2bfu(p6), (short)f2bfu(p7)};

        ot0 = mfma16(va00, pb0, ot0);  // d 0..15 half, keys k0..k0+15
        ot0 = mfma16(va10, pb1, ot0);  // keys k0+16..k0+31
        ot1 = mfma16(va01, pb0, ot1);  // d 16..31 half
        ot1 = mfma16(va11, pb1, ot1);
    }

    const float inv_l = 1.0f / l_run;
    const int b = bh >> 3, head = bh & 7;
    const int qg = qtile * 16 + qi;
    float* orow = o + ((size_t)(b * S_LEN + qg)) * (NH * HD) + head * HD;
    float4 o0 = {ot0[0] * inv_l, ot0[1] * inv_l, ot0[2] * inv_l, ot0[3] * inv_l};
    float4 o1 = {ot1[0] * inv_l, ot1[1] * inv_l, ot1[2] * inv_l, ot1[3] * inv_l};
    *(float4*)(orow + g * 4) = o0;        // d = 4g..4g+3
    *(float4*)(orow + 16 + g * 4) = o1;   // d = 16+4g..+3
}

// ---------------------------------------------------------------------------
// Kernel 3: att_outs = LN(x + o @ Wo + bo). Block = 128 threads, 8 rows.
// ---------------------------------------------------------------------------
__global__ __launch_bounds__(128) void wo_ln(
    const float* __restrict__ o, const float* __restrict__ Wo,
    const float* __restrict__ bo, const float* __restrict__ seq,
    const float* __restrict__ gamma, const float* __restrict__ beta,
    float* __restrict__ att) {
    __shared__ float os[8][NH * HD];
    __shared__ float rs1[2][8], rs2[2][8];
    const int r0 = blockIdx.x * 8;
    const int tid = threadIdx.x;
    const int c = tid;
    for (int e = tid; e < 8 * NH * HD; e += 128) {
        int r = e >> 8, j = e & 255;
        os[r][j] = o[(size_t)(r0 + r) * (NH * HD) + j];
    }
    __syncthreads();
    float acc[8];
#pragma unroll
    for (int r = 0; r < 8; ++r) acc[r] = 0.f;
    for (int j = 0; j < NH * HD; ++j) {
        float wv = Wo[j * QD + c];
#pragma unroll
        for (int r = 0; r < 8; ++r) acc[r] += os[r][j] * wv;
    }
    const float bv = bo[c];
#pragma unroll
    for (int r = 0; r < 8; ++r) {
        int g = r0 + r;
        int b = g >> 10, s = g & 1023;
        acc[r] += bv + seq[(s * BATCH + b) * QD + c];
    }
    const int w = tid >> 6, lane = tid & 63;
#pragma unroll
    for (int r = 0; r < 8; ++r) {
        float s1 = wave_reduce_sum(acc[r]);
        float s2 = wave_reduce_sum(acc[r] * acc[r]);
        if (lane == 0) { rs1[w][r] = s1; rs2[w][r] = s2; }
    }
    __syncthreads();
    const float gm = gamma[c], bt = beta[c];
#pragma unroll
    for (int r = 0; r < 8; ++r) {
        float S1 = rs1[0][r] + rs1[1][r];
        float S2 = rs2[0][r] + rs2[1][r];
        float mu = S1 * (1.0f / QD);
        float var = S2 * (1.0f / QD) - mu * mu;
        float rstd = rsqrtf(var + EPS);
        att[(size_t)(r0 + r) * QD + c] = (acc[r] - mu) * rstd * gm + bt;
    }
}

// ---------------------------------------------------------------------------
// Kernel 4/5: FFN GEMM with ReLU. out[g][f] = relu(A[g][:] @ W + bias[f])
// ---------------------------------------------------------------------------
template <int K>
__global__ __launch_bounds__(128) void ffn_gemm(
    const float* __restrict__ A, const float* __restrict__ W,
    const float* __restrict__ bias, float* __restrict__ out, int N) {
    __shared__ float as[8][128];
    const int r0 = blockIdx.x * 8;
    const int tid = threadIdx.x;
    const int f = blockIdx.y * 128 + tid;
    float acc[8];
#pragma unroll
    for (int r = 0; r < 8; ++r) acc[r] = 0.f;
    for (int kc = 0; kc < K; kc += 128) {
        __syncthreads();
#pragma unroll
        for (int r = 0; r < 8; ++r) as[r][tid] = A[(size_t)(r0 + r) * K + kc + tid];
        __syncthreads();
        for (int j = 0; j < 128; ++j) {
            float wv = W[(size_t)(kc + j) * N + f];
#pragma unroll
            for (int r = 0; r < 8; ++r) acc[r] += as[r][j] * wv;
        }
    }
    const float bv = bias[f];
#pragma unroll
    for (int r = 0; r < 8; ++r) {
        float x = acc[r] + bv;
        out[(size_t)(r0 + r) * N + f] = fmaxf(x, 0.f);
    }
}

// ---------------------------------------------------------------------------
// Kernel 6: out = LN(att + h2 @ W3 + b3), written transposed to [S, B, 128].
// ---------------------------------------------------------------------------
__global__ __launch_bounds__(128) void w3_ln_out(
    const float* __restrict__ h2, const float* __restrict__ W3,
    const float* __restrict__ b3, const float* __restrict__ att,
    const float* __restrict__ gamma, const float* __restrict__ beta,
    float* __restrict__ out) {
    __shared__ float hs[8][FF];
    __shared__ float rs1[2][8], rs2[2][8];
    const int r0 = blockIdx.x * 8;
    const int tid = threadIdx.x;
    const int c = tid;
    for (int e = tid; e < 8 * FF; e += 128) {
        int r = e >> 9, j = e & 511;
        hs[r][j] = h2[(size_t)(r0 + r) * FF + j];
    }
    __syncthreads();
    float acc[8];
#pragma unroll
    for (int r = 0; r < 8; ++r) acc[r] = 0.f;
    for (int j = 0; j < FF; ++j) {
        float wv = W3[j * QD + c];
#pragma unroll
        for (int r = 0; r < 8; ++r) acc[r] += hs[r][j] * wv;
    }
    const float bv = b3[c];
#pragma unroll
    for (int r = 0; r < 8; ++r)
        acc[r] += bv + att[(size_t)(r0 + r) * QD + c];
    const int w = tid >> 6, lane = tid & 63;
#pragma unroll
    for (int r = 0; r < 8; ++r) {
        float s1 = wave_reduce_sum(acc[r]);
        float s2 = wave_reduce_sum(acc[r] * acc[r]);
        if (lane == 0) { rs1[w][r] = s1; rs2[w][r] = s2; }
    }
    __syncthreads();
    const float gm = gamma[c], bt = beta[c];
#pragma unroll
    for (int r = 0; r < 8; ++r) {
        float S1 = rs1[0][r] + rs1[1][r];
        float S2 = rs2[0][r] + rs2[1][r];
        float mu = S1 * (1.0f / QD);
        float var = S2 * (1.0f / QD) - mu * mu;
        float rstd = rsqrtf(var + EPS);
        int g = r0 + r;
        int b = g >> 10, s = g & 1023;
        out[(size_t)(s * BATCH + b) * QD + c] = (acc[r] - mu) * rstd * gm + bt;
    }
}

extern "C" void kernel_launch(void* const* d_in, const int* in_sizes, int n_in,
                              void* d_out, int out_size, void* d_ws, size_t ws_size,
                              hipStream_t stream) {
    const float* seq = (const float*)d_in[0];
    const float* Wq = (const float*)d_in[1];
    const float* bq = (const float*)d_in[2];
    const float* Wk = (const float*)d_in[3];
    const float* bk = (const float*)d_in[4];
    const float* Wv = (const float*)d_in[5];
    const float* bv = (const float*)d_in[6];
    const float* Wo = (const float*)d_in[7];
    const float* bo = (const float*)d_in[8];
    const float* gamma = (const float*)d_in[9];
    const float* beta = (const float*)d_in[10];
    const float* W1 = (const float*)d_in[11];
    const float* b1 = (const float*)d_in[12];
    const float* W2 = (const float*)d_in[13];
    const float* b2 = (const float*)d_in[14];
    const float* W3 = (const float*)d_in[15];
    const float* b3 = (const float*)d_in[16];

    char* wsb = (char*)d_ws;
    // byte layout (72 MB total; h1 overlays dead q/k/v, h2 placed after):
    ushort* q_bf = (ushort*)(wsb);                       // [0, 8 MB)
    ushort* k_bf = (ushort*)(wsb + (8ull << 20));        // [8, 16)
    ushort* vT   = (ushort*)(wsb + (16ull << 20));       // [16, 24)
    float* o     = (float*)(wsb + (24ull << 20));        // [24, 40)
    float* h1    = (float*)(wsb);                        // [0, 32)  (after attn)
    float* h2    = (float*)(wsb + (32ull << 20));        // [32, 64)
    float* att   = (float*)(wsb + (64ull << 20));        // [64, 72)
    float* out = (float*)d_out;

    qkv_proj<<<NROWS / 8, 256, 0, stream>>>(seq, Wq, bq, Wk, bk, Wv, bv, q_bf, k_bf, vT);
    attn_mfma<<<(BATCH * NH) * 16, 256, 0, stream>>>(q_bf, k_bf, vT, o);
    wo_ln<<<NROWS / 8, 128, 0, stream>>>(o, Wo, bo, seq, gamma, beta, att);
    ffn_gemm<QD><<<dim3(NROWS / 8, FF / 128), 128, 0, stream>>>(att, W1, b1, h1, FF);
    ffn_gemm<FF><<<dim3(NROWS / 8, FF / 128), 128, 0, stream>>>(h1, W2, b2, h2, FF);
    w3_ln_out<<<NROWS / 8, 128, 0, stream>>>(h2, W3, b3, att, gamma, beta, out);
}

// Round 3
// 387.517 us; speedup vs baseline: 5.3103x; 1.9159x over previous
//
#include <hip/hip_runtime.h>
#include <hip/hip_bf16.h>

#define S_LEN 1024
#define BATCH 16
#define QD 128
#define NH 8
#define HD 32
#define FF 512
#define NROWS (BATCH * S_LEN)  // 16384 token rows
#define EPS 1e-5f

typedef __attribute__((ext_vector_type(4))) float f32x4;
typedef __attribute__((ext_vector_type(8))) short s16x8;
typedef __attribute__((ext_vector_type(4))) short s16x4;

__device__ __forceinline__ ushort f2bfu(float f) {
    union { float f; unsigned u; } v; v.f = f;
    unsigned r = (v.u + 0x7FFFu + ((v.u >> 16) & 1u)) >> 16;  // RNE
    return (ushort)r;
}

static __device__ __forceinline__ f32x4 mfma16(s16x4 a, s16x4 b, f32x4 c) {
#if __has_builtin(__builtin_amdgcn_mfma_f32_16x16x16bf16_1k)
    return __builtin_amdgcn_mfma_f32_16x16x16bf16_1k(a, b, c, 0, 0, 0);
#else
    asm volatile("v_mfma_f32_16x16x16_bf16 %0, %1, %2, %0" : "+v"(c) : "v"(a), "v"(b));
    return c;
#endif
}

static __device__ __forceinline__ f32x4 mfma32(s16x8 a, s16x8 b, f32x4 c) {
    return __builtin_amdgcn_mfma_f32_16x16x32_bf16(a, b, c, 0, 0, 0);
}

// ---------------------------------------------------------------------------
// Kernel 0: weight prep — bf16 transposed copies (WT[n][k] = W[k][n]).
// Wo 256x128 -> WoT 128x256 | W1 128x512 -> W1T 512x128
// W2 512x512 -> W2T 512x512 | W3 512x128 -> W3T 128x512
// total 425984 elements = 1664 * 256
// ---------------------------------------------------------------------------
__global__ __launch_bounds__(256) void prep_weights(
    const float* __restrict__ Wo, const float* __restrict__ W1,
    const float* __restrict__ W2, const float* __restrict__ W3,
    ushort* __restrict__ WoT, ushort* __restrict__ W1T,
    ushort* __restrict__ W2T, ushort* __restrict__ W3T) {
    int idx = blockIdx.x * 256 + threadIdx.x;
    if (idx < 32768) {
        int n = idx >> 8, k = idx & 255;
        WoT[n * 256 + k] = f2bfu(Wo[k * 128 + n]);
    } else if (idx < 98304) {
        int i = idx - 32768; int n = i >> 7, k = i & 127;
        W1T[n * 128 + k] = f2bfu(W1[k * 512 + n]);
    } else if (idx < 360448) {
        int i = idx - 98304; int n = i >> 9, k = i & 511;
        W2T[n * 512 + k] = f2bfu(W2[k * 512 + n]);
    } else {
        int i = idx - 360448; int n = i >> 9, k = i & 511;
        W3T[n * 512 + k] = f2bfu(W3[k * 128 + n]);
    }
}

// ---------------------------------------------------------------------------
// Kernel 1: fused Q/K/V projection -> bf16 outputs for MFMA attention.
// q_bf: [(b*8+h)*1024+s][32], pre-scaled by 1/sqrt(32)
// k_bf: [(b*8+h)*1024+s][32]
// vT  : [(b*8+h)*32+d][1024]
// ---------------------------------------------------------------------------
__global__ __launch_bounds__(256) void qkv_proj(
    const float* __restrict__ seq,
    const float* __restrict__ Wq, const float* __restrict__ bq,
    const float* __restrict__ Wk, const float* __restrict__ bk,
    const float* __restrict__ Wv, const float* __restrict__ bv,
    ushort* __restrict__ q_bf, ushort* __restrict__ k_bf, ushort* __restrict__ vT) {
    __shared__ float xs[8][QD];
    const int r0 = blockIdx.x * 8;
    const int tid = threadIdx.x;
    for (int e = tid; e < 8 * QD; e += 256) {
        int r = e >> 7, c = e & 127;
        int g = r0 + r;
        int b = g >> 10, s = g & 1023;
        xs[r][c] = seq[(s * BATCH + b) * QD + c];
    }
    __syncthreads();
    const int h = tid >> 5, d = tid & 31;
    float aq[8], ak[8], av[8];
#pragma unroll
    for (int r = 0; r < 8; ++r) { aq[r] = 0.f; ak[r] = 0.f; av[r] = 0.f; }
    const float* wq = Wq + h * QD * HD + d;
    const float* wk = Wk + h * QD * HD + d;
    const float* wv = Wv + h * QD * HD + d;
    for (int c = 0; c < QD; ++c) {
        float wqv = wq[c * HD], wkv = wk[c * HD], wvv = wv[c * HD];
#pragma unroll
        for (int r = 0; r < 8; ++r) {
            float x = xs[r][c];
            aq[r] += x * wqv;
            ak[r] += x * wkv;
            av[r] += x * wvv;
        }
    }
    const float bqv = bq[h * HD + d], bkv = bk[h * HD + d], bvv = bv[h * HD + d];
    const float SCALE = 0.17677669529663687f;  // 1/sqrt(32)
    const int b = r0 >> 10, s0 = r0 & 1023;
    const int bh = b * NH + h;
    s16x8 pv;
#pragma unroll
    for (int r = 0; r < 8; ++r) {
        size_t idx = ((size_t)bh * S_LEN + (s0 + r)) * HD + d;
        q_bf[idx] = f2bfu((aq[r] + bqv) * SCALE);
        k_bf[idx] = f2bfu(ak[r] + bkv);
        pv[r] = (short)f2bfu(av[r] + bvv);
    }
    *(s16x8*)(vT + ((size_t)bh * HD + d) * S_LEN + s0) = pv;
}

// ---------------------------------------------------------------------------
// Kernel 2: flash-style MFMA attention. One wave per 16-query tile; no LDS.
// o_bf layout: [b*S+s][256] bf16 (heads concatenated)
// ---------------------------------------------------------------------------
__global__ __launch_bounds__(256) void attn_mfma(
    const ushort* __restrict__ qb, const ushort* __restrict__ kb,
    const ushort* __restrict__ vtb, ushort* __restrict__ o_bf) {
    const int tid = threadIdx.x;
    const int w = tid >> 6, lane = tid & 63;
    const int g = lane >> 4, qi = lane & 15;
    const int bh = blockIdx.x >> 4;
    const int qtile = (blockIdx.x & 15) * 4 + w;

    const ushort* Kb = kb + (size_t)bh * S_LEN * HD;
    const ushort* VTb = vtb + (size_t)bh * HD * S_LEN;

    const s16x8 qf = *(const s16x8*)(qb + ((size_t)bh * S_LEN + qtile * 16 + qi) * HD + g * 8);

    f32x4 ot0 = {0.f, 0.f, 0.f, 0.f};
    f32x4 ot1 = {0.f, 0.f, 0.f, 0.f};
    float m_run = -1e30f, l_run = 0.f;
    const f32x4 zero = {0.f, 0.f, 0.f, 0.f};

#pragma unroll 2
    for (int it = 0; it < S_LEN / 32; ++it) {
        const int k0 = it * 32;
        s16x8 ka0 = *(const s16x8*)(Kb + (size_t)(k0 + qi) * HD + g * 8);
        s16x8 ka1 = *(const s16x8*)(Kb + (size_t)(k0 + 16 + qi) * HD + g * 8);
        s16x4 va00 = *(const s16x4*)(VTb + (size_t)qi * S_LEN + k0 + g * 4);
        s16x4 va01 = *(const s16x4*)(VTb + (size_t)(16 + qi) * S_LEN + k0 + g * 4);
        s16x4 va10 = *(const s16x4*)(VTb + (size_t)qi * S_LEN + k0 + 16 + g * 4);
        s16x4 va11 = *(const s16x4*)(VTb + (size_t)(16 + qi) * S_LEN + k0 + 16 + g * 4);

        f32x4 st0 = mfma32(ka0, qf, zero);
        f32x4 st1 = mfma32(ka1, qf, zero);

        float mt = fmaxf(fmaxf(fmaxf(st0[0], st0[1]), fmaxf(st0[2], st0[3])),
                         fmaxf(fmaxf(st1[0], st1[1]), fmaxf(st1[2], st1[3])));
        mt = fmaxf(mt, __shfl_xor(mt, 16, 64));
        mt = fmaxf(mt, __shfl_xor(mt, 32, 64));
        const float m_new = fmaxf(m_run, mt);
        const float alpha = __expf(m_run - m_new);
        float p0 = __expf(st0[0] - m_new), p1 = __expf(st0[1] - m_new);
        float p2 = __expf(st0[2] - m_new), p3 = __expf(st0[3] - m_new);
        float p4 = __expf(st1[0] - m_new), p5 = __expf(st1[1] - m_new);
        float p6 = __expf(st1[2] - m_new), p7 = __expf(st1[3] - m_new);
        float lt = ((p0 + p1) + (p2 + p3)) + ((p4 + p5) + (p6 + p7));
        lt += __shfl_xor(lt, 16, 64);
        lt += __shfl_xor(lt, 32, 64);
        l_run = l_run * alpha + lt;
        m_run = m_new;
#pragma unroll
        for (int r = 0; r < 4; ++r) { ot0[r] *= alpha; ot1[r] *= alpha; }

        s16x4 pb0 = {(short)f2bfu(p0), (short)f2bfu(p1), (short)f2bfu(p2), (short)f2bfu(p3)};
        s16x4 pb1 = {(short)f2bfu(p4), (short)f2bfu(p5), (short)f2bfu(p6), (short)f2bfu(p7)};

        ot0 = mfma16(va00, pb0, ot0);
        ot0 = mfma16(va10, pb1, ot0);
        ot1 = mfma16(va01, pb0, ot1);
        ot1 = mfma16(va11, pb1, ot1);
    }

    const float inv_l = 1.0f / l_run;
    const int b = bh >> 3, head = bh & 7;
    const int qg = qtile * 16 + qi;
    ushort* orow = o_bf + ((size_t)(b * S_LEN + qg)) * (NH * HD) + head * HD;
    ushort4 ob0 = {f2bfu(ot0[0] * inv_l), f2bfu(ot0[1] * inv_l),
                   f2bfu(ot0[2] * inv_l), f2bfu(ot0[3] * inv_l)};
    ushort4 ob1 = {f2bfu(ot1[0] * inv_l), f2bfu(ot1[1] * inv_l),
                   f2bfu(ot1[2] * inv_l), f2bfu(ot1[3] * inv_l)};
    *(ushort4*)(orow + g * 4) = ob0;
    *(ushort4*)(orow + 16 + g * 4) = ob1;
}

// ---------------------------------------------------------------------------
// Kernel 3: wo_ln_mfma — att = LN(x + o @ Wo + bo); emits f32 + bf16 copies.
// Swapped MFMA: A = WoT rows (n), B = o token rows. Lane holds token=lane&15,
// n = 16f + 4g + r. LN reduce = in-lane + shfl_xor(16,32).
// ---------------------------------------------------------------------------
__global__ __launch_bounds__(256) void wo_ln_mfma(
    const ushort* __restrict__ o_bf, const ushort* __restrict__ WoT,
    const float* __restrict__ bo, const float* __restrict__ seq,
    const float* __restrict__ gamma, const float* __restrict__ beta,
    float* __restrict__ att, ushort* __restrict__ att_bf) {
    const int lane = threadIdx.x & 63;
    const int w = threadIdx.x >> 6;
    const int qi = lane & 15, g = lane >> 4;
    const int tok = (blockIdx.x * 4 + w) * 16 + qi;

    f32x4 acc[8];
#pragma unroll
    for (int f = 0; f < 8; ++f) acc[f] = (f32x4){0.f, 0.f, 0.f, 0.f};

    const ushort* bptr = o_bf + (size_t)tok * 256 + g * 8;
    const ushort* aptr = WoT + (size_t)qi * 256 + g * 8;
#pragma unroll 4
    for (int kk = 0; kk < 256; kk += 32) {
        s16x8 bfrag = *(const s16x8*)(bptr + kk);
#pragma unroll
        for (int f = 0; f < 8; ++f) {
            s16x8 afrag = *(const s16x8*)(aptr + (size_t)(16 * f) * 256 + kk);
            acc[f] = mfma32(afrag, bfrag, acc[f]);
        }
    }

    const int b = tok >> 10, s = tok & 1023;
    const float* xrow = seq + (size_t)(s * BATCH + b) * QD;
    float sum = 0.f, sumsq = 0.f;
#pragma unroll
    for (int f = 0; f < 8; ++f) {
        const int c = 16 * f + 4 * g;
        float4 bv = *(const float4*)(bo + c);
        float4 xv = *(const float4*)(xrow + c);
        acc[f][0] += bv.x + xv.x;
        acc[f][1] += bv.y + xv.y;
        acc[f][2] += bv.z + xv.z;
        acc[f][3] += bv.w + xv.w;
#pragma unroll
        for (int r = 0; r < 4; ++r) { sum += acc[f][r]; sumsq += acc[f][r] * acc[f][r]; }
    }
    sum += __shfl_xor(sum, 16, 64);
    sum += __shfl_xor(sum, 32, 64);
    sumsq += __shfl_xor(sumsq, 16, 64);
    sumsq += __shfl_xor(sumsq, 32, 64);
    const float mu = sum * (1.0f / QD);
    const float var = sumsq * (1.0f / QD) - mu * mu;
    const float rstd = rsqrtf(var + EPS);

#pragma unroll
    for (int f = 0; f < 8; ++f) {
        const int c = 16 * f + 4 * g;
        float4 gm = *(const float4*)(gamma + c);
        float4 bt = *(const float4*)(beta + c);
        float4 ov;
        ov.x = (acc[f][0] - mu) * rstd * gm.x + bt.x;
        ov.y = (acc[f][1] - mu) * rstd * gm.y + bt.y;
        ov.z = (acc[f][2] - mu) * rstd * gm.z + bt.z;
        ov.w = (acc[f][3] - mu) * rstd * gm.w + bt.w;
        *(float4*)(att + (size_t)tok * QD + c) = ov;
        ushort4 pv = {f2bfu(ov.x), f2bfu(ov.y), f2bfu(ov.z), f2bfu(ov.w)};
        *(ushort4*)(att_bf + (size_t)tok * QD + c) = pv;
    }
}

// ---------------------------------------------------------------------------
// Kernel 4/5: ffn_mfma — out_bf = relu(act_bf @ WT^T + bias). Wave: 16 tok x 128 n.
// ---------------------------------------------------------------------------
template <int K>
__global__ __launch_bounds__(256) void ffn_mfma(
    const ushort* __restrict__ act, const ushort* __restrict__ WT,
    const float* __restrict__ bias, ushort* __restrict__ out, int N) {
    const int lane = threadIdx.x & 63;
    const int w = threadIdx.x >> 6;
    const int qi = lane & 15, g = lane >> 4;
    const int tok = (blockIdx.x * 4 + w) * 16 + qi;
    const int n0 = blockIdx.y * 128;

    f32x4 acc[8];
#pragma unroll
    for (int f = 0; f < 8; ++f) acc[f] = (f32x4){0.f, 0.f, 0.f, 0.f};

    const ushort* bptr = act + (size_t)tok * K + g * 8;
    const ushort* aptr = WT + (size_t)(n0 + qi) * K + g * 8;
#pragma unroll 4
    for (int kk = 0; kk < K; kk += 32) {
        s16x8 bfrag = *(const s16x8*)(bptr + kk);
#pragma unroll
        for (int f = 0; f < 8; ++f) {
            s16x8 afrag = *(const s16x8*)(aptr + (size_t)(16 * f) * K + kk);
            acc[f] = mfma32(afrag, bfrag, acc[f]);
        }
    }
#pragma unroll
    for (int f = 0; f < 8; ++f) {
        const int c = n0 + 16 * f + 4 * g;
        float4 bv = *(const float4*)(bias + c);
        ushort4 pv;
        pv.x = f2bfu(fmaxf(acc[f][0] + bv.x, 0.f));
        pv.y = f2bfu(fmaxf(acc[f][1] + bv.y, 0.f));
        pv.z = f2bfu(fmaxf(acc[f][2] + bv.z, 0.f));
        pv.w = f2bfu(fmaxf(acc[f][3] + bv.w, 0.f));
        *(ushort4*)(out + (size_t)tok * N + c) = pv;
    }
}

// ---------------------------------------------------------------------------
// Kernel 6: w3_ln_mfma — out = LN(att + h2 @ W3 + b3), written to [S,B,128] f32.
// ---------------------------------------------------------------------------
__global__ __launch_bounds__(256) void w3_ln_mfma(
    const ushort* __restrict__ h2, const ushort* __restrict__ W3T,
    const float* __restrict__ b3, const float* __restrict__ att,
    const float* __restrict__ gamma, const float* __restrict__ beta,
    float* __restrict__ out) {
    const int lane = threadIdx.x & 63;
    const int w = threadIdx.x >> 6;
    const int qi = lane & 15, g = lane >> 4;
    const int tok = (blockIdx.x * 4 + w) * 16 + qi;

    f32x4 acc[8];
#pragma unroll
    for (int f = 0; f < 8; ++f) acc[f] = (f32x4){0.f, 0.f, 0.f, 0.f};

    const ushort* bptr = h2 + (size_t)tok * FF + g * 8;
    const ushort* aptr = W3T + (size_t)qi * FF + g * 8;
#pragma unroll 4
    for (int kk = 0; kk < FF; kk += 32) {
        s16x8 bfrag = *(const s16x8*)(bptr + kk);
#pragma unroll
        for (int f = 0; f < 8; ++f) {
            s16x8 afrag = *(const s16x8*)(aptr + (size_t)(16 * f) * FF + kk);
            acc[f] = mfma32(afrag, bfrag, acc[f]);
        }
    }

    float sum = 0.f, sumsq = 0.f;
#pragma unroll
    for (int f = 0; f < 8; ++f) {
        const int c = 16 * f + 4 * g;
        float4 bv = *(const float4*)(b3 + c);
        float4 xv = *(const float4*)(att + (size_t)tok * QD + c);
        acc[f][0] += bv.x + xv.x;
        acc[f][1] += bv.y + xv.y;
        acc[f][2] += bv.z + xv.z;
        acc[f][3] += bv.w + xv.w;
#pragma unroll
        for (int r = 0; r < 4; ++r) { sum += acc[f][r]; sumsq += acc[f][r] * acc[f][r]; }
    }
    sum += __shfl_xor(sum, 16, 64);
    sum += __shfl_xor(sum, 32, 64);
    sumsq += __shfl_xor(sumsq, 16, 64);
    sumsq += __shfl_xor(sumsq, 32, 64);
    const float mu = sum * (1.0f / QD);
    const float var = sumsq * (1.0f / QD) - mu * mu;
    const float rstd = rsqrtf(var + EPS);

    const int b = tok >> 10, s = tok & 1023;
    float* orow = out + (size_t)(s * BATCH + b) * QD;
#pragma unroll
    for (int f = 0; f < 8; ++f) {
        const int c = 16 * f + 4 * g;
        float4 gm = *(const float4*)(gamma + c);
        float4 bt = *(const float4*)(beta + c);
        float4 ov;
        ov.x = (acc[f][0] - mu) * rstd * gm.x + bt.x;
        ov.y = (acc[f][1] - mu) * rstd * gm.y + bt.y;
        ov.z = (acc[f][2] - mu) * rstd * gm.z + bt.z;
        ov.w = (acc[f][3] - mu) * rstd * gm.w + bt.w;
        *(float4*)(orow + c) = ov;
    }
}

extern "C" void kernel_launch(void* const* d_in, const int* in_sizes, int n_in,
                              void* d_out, int out_size, void* d_ws, size_t ws_size,
                              hipStream_t stream) {
    const float* seq = (const float*)d_in[0];
    const float* Wq = (const float*)d_in[1];
    const float* bq = (const float*)d_in[2];
    const float* Wk = (const float*)d_in[3];
    const float* bk = (const float*)d_in[4];
    const float* Wv = (const float*)d_in[5];
    const float* bv = (const float*)d_in[6];
    const float* Wo = (const float*)d_in[7];
    const float* bo = (const float*)d_in[8];
    const float* gamma = (const float*)d_in[9];
    const float* beta = (const float*)d_in[10];
    const float* W1 = (const float*)d_in[11];
    const float* b1 = (const float*)d_in[12];
    const float* W2 = (const float*)d_in[13];
    const float* b2 = (const float*)d_in[14];
    const float* W3 = (const float*)d_in[15];
    const float* b3 = (const float*)d_in[16];

    char* wsb = (char*)d_ws;
    // byte layout (~45 MB): h1 overlays q_bf+k_bf, h2 overlays vT+o_bf.
    ushort* q_bf  = (ushort*)(wsb);                    // [0, 8 MB)
    ushort* k_bf  = (ushort*)(wsb + (8ull << 20));     // [8, 16)
    ushort* vT    = (ushort*)(wsb + (16ull << 20));    // [16, 24)
    ushort* o_bf  = (ushort*)(wsb + (24ull << 20));    // [24, 32)
    float*  att   = (float*)(wsb + (32ull << 20));     // [32, 40)
    ushort* att_bf= (ushort*)(wsb + (40ull << 20));    // [40, 44)
    ushort* h1_bf = (ushort*)(wsb);                    // [0, 16) after attn
    ushort* h2_bf = (ushort*)(wsb + (16ull << 20));    // [16, 32) after wo_ln
    ushort* WoT   = (ushort*)(wsb + (44ull << 20));    // 64 KB
    ushort* W1T   = WoT + 32768;                       // 128 KB
    ushort* W2T   = W1T + 65536;                       // 512 KB
    ushort* W3T   = W2T + 262144;                      // 128 KB
    float* out = (float*)d_out;

    prep_weights<<<1664, 256, 0, stream>>>(Wo, W1, W2, W3, WoT, W1T, W2T, W3T);
    qkv_proj<<<NROWS / 8, 256, 0, stream>>>(seq, Wq, bq, Wk, bk, Wv, bv, q_bf, k_bf, vT);
    attn_mfma<<<(BATCH * NH) * 16, 256, 0, stream>>>(q_bf, k_bf, vT, o_bf);
    wo_ln_mfma<<<NROWS / 64, 256, 0, stream>>>(o_bf, WoT, bo, seq, gamma, beta, att, att_bf);
    ffn_mfma<QD><<<dim3(NROWS / 64, 4), 256, 0, stream>>>(att_bf, W1T, b1, h1_bf, FF);
    ffn_mfma<FF><<<dim3(NROWS / 64, 4), 256, 0, stream>>>(h1_bf, W2T, b2, h2_bf, FF);
    w3_ln_mfma<<<NROWS / 64, 256, 0, stream>>>(h2_bf, W3T, b3, att, gamma, beta, out);
}

// Round 4
// 387.262 us; speedup vs baseline: 5.3138x; 1.0007x over previous
//
#include <hip/hip_runtime.h>
#include <hip/hip_bf16.h>

#define S_LEN 1024
#define BATCH 16
#define QD 128
#define NH 8
#define HD 32
#define FF 512
#define NROWS (BATCH * S_LEN)  // 16384 token rows
#define EPS 1e-5f

typedef __attribute__((ext_vector_type(4))) float f32x4;
typedef __attribute__((ext_vector_type(8))) short s16x8;
typedef __attribute__((ext_vector_type(4))) short s16x4;

__device__ __forceinline__ ushort f2bfu(float f) {
    union { float f; unsigned u; } v; v.f = f;
    unsigned r = (v.u + 0x7FFFu + ((v.u >> 16) & 1u)) >> 16;  // RNE
    return (ushort)r;
}

__device__ __forceinline__ float exp2_fast(float x) {
#if __has_builtin(__builtin_amdgcn_exp2f)
    return __builtin_amdgcn_exp2f(x);
#else
    float r;
    asm("v_exp_f32 %0, %1" : "=v"(r) : "v"(x));
    return r;
#endif
}

__device__ __forceinline__ unsigned pk_bf16(float a, float b) {
    union { __hip_bfloat162 h; unsigned u; } c;
    c.h = __float22bfloat162_rn(make_float2(a, b));
    return c.u;
}

static __device__ __forceinline__ f32x4 mfma16(s16x4 a, s16x4 b, f32x4 c) {
#if __has_builtin(__builtin_amdgcn_mfma_f32_16x16x16bf16_1k)
    return __builtin_amdgcn_mfma_f32_16x16x16bf16_1k(a, b, c, 0, 0, 0);
#else
    asm volatile("v_mfma_f32_16x16x16_bf16 %0, %1, %2, %0" : "+v"(c) : "v"(a), "v"(b));
    return c;
#endif
}

static __device__ __forceinline__ f32x4 mfma32(s16x8 a, s16x8 b, f32x4 c) {
    return __builtin_amdgcn_mfma_f32_16x16x32_bf16(a, b, c, 0, 0, 0);
}

// ---------------------------------------------------------------------------
// Kernel 0: weight prep — bf16 transposed copies (WT[n][k] = W[k][n]).
// ---------------------------------------------------------------------------
__global__ __launch_bounds__(256) void prep_weights(
    const float* __restrict__ Wo, const float* __restrict__ W1,
    const float* __restrict__ W2, const float* __restrict__ W3,
    ushort* __restrict__ WoT, ushort* __restrict__ W1T,
    ushort* __restrict__ W2T, ushort* __restrict__ W3T) {
    int idx = blockIdx.x * 256 + threadIdx.x;
    if (idx < 32768) {
        int n = idx >> 8, k = idx & 255;
        WoT[n * 256 + k] = f2bfu(Wo[k * 128 + n]);
    } else if (idx < 98304) {
        int i = idx - 32768; int n = i >> 7, k = i & 127;
        W1T[n * 128 + k] = f2bfu(W1[k * 512 + n]);
    } else if (idx < 360448) {
        int i = idx - 98304; int n = i >> 9, k = i & 511;
        W2T[n * 512 + k] = f2bfu(W2[k * 512 + n]);
    } else {
        int i = idx - 360448; int n = i >> 9, k = i & 511;
        W3T[n * 512 + k] = f2bfu(W3[k * 128 + n]);
    }
}

// ---------------------------------------------------------------------------
// Kernel 1: fused Q/K/V projection -> bf16 outputs for MFMA attention.
// q_bf pre-scaled by log2(e)/sqrt(32)  (attention works in exp2 domain)
// ---------------------------------------------------------------------------
__global__ __launch_bounds__(256) void qkv_proj(
    const float* __restrict__ seq,
    const float* __restrict__ Wq, const float* __restrict__ bq,
    const float* __restrict__ Wk, const float* __restrict__ bk,
    const float* __restrict__ Wv, const float* __restrict__ bv,
    ushort* __restrict__ q_bf, ushort* __restrict__ k_bf, ushort* __restrict__ vT) {
    __shared__ float xs[8][QD];
    const int r0 = blockIdx.x * 8;
    const int tid = threadIdx.x;
    for (int e = tid; e < 8 * QD; e += 256) {
        int r = e >> 7, c = e & 127;
        int g = r0 + r;
        int b = g >> 10, s = g & 1023;
        xs[r][c] = seq[(s * BATCH + b) * QD + c];
    }
    __syncthreads();
    const int h = tid >> 5, d = tid & 31;
    float aq[8], ak[8], av[8];
#pragma unroll
    for (int r = 0; r < 8; ++r) { aq[r] = 0.f; ak[r] = 0.f; av[r] = 0.f; }
    const float* wq = Wq + h * QD * HD + d;
    const float* wk = Wk + h * QD * HD + d;
    const float* wv = Wv + h * QD * HD + d;
    for (int c = 0; c < QD; ++c) {
        float wqv = wq[c * HD], wkv = wk[c * HD], wvv = wv[c * HD];
#pragma unroll
        for (int r = 0; r < 8; ++r) {
            float x = xs[r][c];
            aq[r] += x * wqv;
            ak[r] += x * wkv;
            av[r] += x * wvv;
        }
    }
    const float bqv = bq[h * HD + d], bkv = bk[h * HD + d], bvv = bv[h * HD + d];
    const float SCALE = 0.25503491f;  // log2(e)/sqrt(32)
    const int b = r0 >> 10, s0 = r0 & 1023;
    const int bh = b * NH + h;
    s16x8 pv;
#pragma unroll
    for (int r = 0; r < 8; ++r) {
        size_t idx = ((size_t)bh * S_LEN + (s0 + r)) * HD + d;
        q_bf[idx] = f2bfu((aq[r] + bqv) * SCALE);
        k_bf[idx] = f2bfu(ak[r] + bkv);
        pv[r] = (short)f2bfu(av[r] + bvv);
    }
    *(s16x8*)(vT + ((size_t)bh * HD + d) * S_LEN + s0) = pv;
}

// ---------------------------------------------------------------------------
// Kernel 2: flash-style MFMA attention, KBLK=64, defer-max, exp2-domain.
// One wave per 16-query tile; no LDS. XCD-swizzled blockIdx.
// ---------------------------------------------------------------------------
struct Frags {
    s16x8 ka[4];       // K rows (k0+16t+qi), cols 8g..8g+7
    s16x4 va[2][4];    // V^T rows 16h+qi, cols k0+16t+4g..+3
};

__device__ __forceinline__ void load_frags(Frags& f, const ushort* Kb,
                                           const ushort* VTb, int k0, int qi, int g) {
#pragma unroll
    for (int t = 0; t < 4; ++t)
        f.ka[t] = *(const s16x8*)(Kb + (size_t)(k0 + 16 * t + qi) * HD + g * 8);
#pragma unroll
    for (int h = 0; h < 2; ++h)
#pragma unroll
        for (int t = 0; t < 4; ++t)
            f.va[h][t] = *(const s16x4*)(VTb + (size_t)(16 * h + qi) * S_LEN + k0 + 16 * t + g * 4);
}

__device__ __forceinline__ void attn_tile(const Frags& F, const s16x8& qf,
                                          f32x4& ot0, f32x4& ot1,
                                          float& m_run, float& l_run) {
    const f32x4 zero = {0.f, 0.f, 0.f, 0.f};
    f32x4 st[4];
    __builtin_amdgcn_s_setprio(1);
#pragma unroll
    for (int t = 0; t < 4; ++t) st[t] = mfma32(F.ka[t], qf, zero);
    __builtin_amdgcn_s_setprio(0);

    // local max (tree)
    float a0 = fmaxf(fmaxf(st[0][0], st[0][1]), fmaxf(st[0][2], st[0][3]));
    float a1 = fmaxf(fmaxf(st[1][0], st[1][1]), fmaxf(st[1][2], st[1][3]));
    float a2 = fmaxf(fmaxf(st[2][0], st[2][1]), fmaxf(st[2][2], st[2][3]));
    float a3 = fmaxf(fmaxf(st[3][0], st[3][1]), fmaxf(st[3][2], st[3][3]));
    float pmax = fmaxf(fmaxf(a0, a1), fmaxf(a2, a3));

    // defer-max: only rescale when the running max grew by > 8 (log2 units)
    if (!__all(pmax <= m_run + 8.0f)) {
        float mt = pmax;
        mt = fmaxf(mt, __shfl_xor(mt, 16, 64));
        mt = fmaxf(mt, __shfl_xor(mt, 32, 64));
        float m_new = fmaxf(m_run, mt);
        float alpha = exp2_fast(m_run - m_new);
        l_run *= alpha;
#pragma unroll
        for (int r = 0; r < 4; ++r) { ot0[r] *= alpha; ot1[r] *= alpha; }
        m_run = m_new;
    }

    float p[4][4];
#pragma unroll
    for (int t = 0; t < 4; ++t)
#pragma unroll
        for (int r = 0; r < 4; ++r) p[t][r] = exp2_fast(st[t][r] - m_run);
    float s0 = (p[0][0] + p[0][1]) + (p[0][2] + p[0][3]);
    float s1 = (p[1][0] + p[1][1]) + (p[1][2] + p[1][3]);
    float s2 = (p[2][0] + p[2][1]) + (p[2][2] + p[2][3]);
    float s3 = (p[3][0] + p[3][1]) + (p[3][2] + p[3][3]);
    l_run += (s0 + s1) + (s2 + s3);  // per-lane partial; cross-lane at end

    union { s16x4 v; uint2 u; } pb[4];
#pragma unroll
    for (int t = 0; t < 4; ++t) {
        pb[t].u.x = pk_bf16(p[t][0], p[t][1]);
        pb[t].u.y = pk_bf16(p[t][2], p[t][3]);
    }
    __builtin_amdgcn_s_setprio(1);
#pragma unroll
    for (int t = 0; t < 4; ++t) {
        ot0 = mfma16(F.va[0][t], pb[t].v, ot0);
        ot1 = mfma16(F.va[1][t], pb[t].v, ot1);
    }
    __builtin_amdgcn_s_setprio(0);
}

__global__ __launch_bounds__(256) void attn_mfma(
    const ushort* __restrict__ qb, const ushort* __restrict__ kb,
    const ushort* __restrict__ vtb, ushort* __restrict__ o_bf) {
    const int tid = threadIdx.x;
    const int w = tid >> 6, lane = tid & 63;
    const int g = lane >> 4, qi = lane & 15;
    // XCD-aware swizzle (2048 blocks, 8 XCDs): all 16 blocks of one bh on one XCD
    const int bid = blockIdx.x;
    const int swz = (bid & 7) * 256 + (bid >> 3);
    const int bh = swz >> 4;
    const int qtile = (swz & 15) * 4 + w;

    const ushort* Kb = kb + (size_t)bh * S_LEN * HD;
    const ushort* VTb = vtb + (size_t)bh * HD * S_LEN;

    const s16x8 qf = *(const s16x8*)(qb + ((size_t)bh * S_LEN + qtile * 16 + qi) * HD + g * 8);

    f32x4 ot0 = {0.f, 0.f, 0.f, 0.f};
    f32x4 ot1 = {0.f, 0.f, 0.f, 0.f};
    float m_run = -1e30f, l_run = 0.f;

    Frags A, B;
    load_frags(A, Kb, VTb, 0, qi, g);
#pragma unroll 1
    for (int it = 0; it < 16; it += 2) {
        load_frags(B, Kb, VTb, (it + 1) * 64, qi, g);
        attn_tile(A, qf, ot0, ot1, m_run, l_run);
        if (it + 2 < 16) load_frags(A, Kb, VTb, (it + 2) * 64, qi, g);
        attn_tile(B, qf, ot0, ot1, m_run, l_run);
    }

    l_run += __shfl_xor(l_run, 16, 64);
    l_run += __shfl_xor(l_run, 32, 64);
    const float inv_l = 1.0f / l_run;
    const int b = bh >> 3, head = bh & 7;
    const int qg = qtile * 16 + qi;
    ushort* orow = o_bf + ((size_t)(b * S_LEN + qg)) * (NH * HD) + head * HD;
    ushort4 ob0 = {f2bfu(ot0[0] * inv_l), f2bfu(ot0[1] * inv_l),
                   f2bfu(ot0[2] * inv_l), f2bfu(ot0[3] * inv_l)};
    ushort4 ob1 = {f2bfu(ot1[0] * inv_l), f2bfu(ot1[1] * inv_l),
                   f2bfu(ot1[2] * inv_l), f2bfu(ot1[3] * inv_l)};
    *(ushort4*)(orow + g * 4) = ob0;
    *(ushort4*)(orow + 16 + g * 4) = ob1;
}

// ---------------------------------------------------------------------------
// Kernel 3: wo_ln_mfma — att = LN(x + o @ Wo + bo); emits f32 + bf16 copies.
// ---------------------------------------------------------------------------
__global__ __launch_bounds__(256) void wo_ln_mfma(
    const ushort* __restrict__ o_bf, const ushort* __restrict__ WoT,
    const float* __restrict__ bo, const float* __restrict__ seq,
    const float* __restrict__ gamma, const float* __restrict__ beta,
    float* __restrict__ att, ushort* __restrict__ att_bf) {
    const int lane = threadIdx.x & 63;
    const int w = threadIdx.x >> 6;
    const int qi = lane & 15, g = lane >> 4;
    const int tok = (blockIdx.x * 4 + w) * 16 + qi;

    f32x4 acc[8];
#pragma unroll
    for (int f = 0; f < 8; ++f) acc[f] = (f32x4){0.f, 0.f, 0.f, 0.f};

    const ushort* bptr = o_bf + (size_t)tok * 256 + g * 8;
    const ushort* aptr = WoT + (size_t)qi * 256 + g * 8;
#pragma unroll 4
    for (int kk = 0; kk < 256; kk += 32) {
        s16x8 bfrag = *(const s16x8*)(bptr + kk);
#pragma unroll
        for (int f = 0; f < 8; ++f) {
            s16x8 afrag = *(const s16x8*)(aptr + (size_t)(16 * f) * 256 + kk);
            acc[f] = mfma32(afrag, bfrag, acc[f]);
        }
    }

    const int b = tok >> 10, s = tok & 1023;
    const float* xrow = seq + (size_t)(s * BATCH + b) * QD;
    float sum = 0.f, sumsq = 0.f;
#pragma unroll
    for (int f = 0; f < 8; ++f) {
        const int c = 16 * f + 4 * g;
        float4 bv = *(const float4*)(bo + c);
        float4 xv = *(const float4*)(xrow + c);
        acc[f][0] += bv.x + xv.x;
        acc[f][1] += bv.y + xv.y;
        acc[f][2] += bv.z + xv.z;
        acc[f][3] += bv.w + xv.w;
#pragma unroll
        for (int r = 0; r < 4; ++r) { sum += acc[f][r]; sumsq += acc[f][r] * acc[f][r]; }
    }
    sum += __shfl_xor(sum, 16, 64);
    sum += __shfl_xor(sum, 32, 64);
    sumsq += __shfl_xor(sumsq, 16, 64);
    sumsq += __shfl_xor(sumsq, 32, 64);
    const float mu = sum * (1.0f / QD);
    const float var = sumsq * (1.0f / QD) - mu * mu;
    const float rstd = rsqrtf(var + EPS);

#pragma unroll
    for (int f = 0; f < 8; ++f) {
        const int c = 16 * f + 4 * g;
        float4 gm = *(const float4*)(gamma + c);
        float4 bt = *(const float4*)(beta + c);
        float4 ov;
        ov.x = (acc[f][0] - mu) * rstd * gm.x + bt.x;
        ov.y = (acc[f][1] - mu) * rstd * gm.y + bt.y;
        ov.z = (acc[f][2] - mu) * rstd * gm.z + bt.z;
        ov.w = (acc[f][3] - mu) * rstd * gm.w + bt.w;
        *(float4*)(att + (size_t)tok * QD + c) = ov;
        ushort4 pv = {f2bfu(ov.x), f2bfu(ov.y), f2bfu(ov.z), f2bfu(ov.w)};
        *(ushort4*)(att_bf + (size_t)tok * QD + c) = pv;
    }
}

// ---------------------------------------------------------------------------
// Kernel 4/5: ffn_mfma — out_bf = relu(act_bf @ WT^T + bias).
// ---------------------------------------------------------------------------
template <int K>
__global__ __launch_bounds__(256) void ffn_mfma(
    const ushort* __restrict__ act, const ushort* __restrict__ WT,
    const float* __restrict__ bias, ushort* __restrict__ out, int N) {
    const int lane = threadIdx.x & 63;
    const int w = threadIdx.x >> 6;
    const int qi = lane & 15, g = lane >> 4;
    const int tok = (blockIdx.x * 4 + w) * 16 + qi;
    const int n0 = blockIdx.y * 128;

    f32x4 acc[8];
#pragma unroll
    for (int f = 0; f < 8; ++f) acc[f] = (f32x4){0.f, 0.f, 0.f, 0.f};

    const ushort* bptr = act + (size_t)tok * K + g * 8;
    const ushort* aptr = WT + (size_t)(n0 + qi) * K + g * 8;
#pragma unroll 4
    for (int kk = 0; kk < K; kk += 32) {
        s16x8 bfrag = *(const s16x8*)(bptr + kk);
#pragma unroll
        for (int f = 0; f < 8; ++f) {
            s16x8 afrag = *(const s16x8*)(aptr + (size_t)(16 * f) * K + kk);
            acc[f] = mfma32(afrag, bfrag, acc[f]);
        }
    }
#pragma unroll
    for (int f = 0; f < 8; ++f) {
        const int c = n0 + 16 * f + 4 * g;
        float4 bv = *(const float4*)(bias + c);
        ushort4 pv;
        pv.x = f2bfu(fmaxf(acc[f][0] + bv.x, 0.f));
        pv.y = f2bfu(fmaxf(acc[f][1] + bv.y, 0.f));
        pv.z = f2bfu(fmaxf(acc[f][2] + bv.z, 0.f));
        pv.w = f2bfu(fmaxf(acc[f][3] + bv.w, 0.f));
        *(ushort4*)(out + (size_t)tok * N + c) = pv;
    }
}

// ---------------------------------------------------------------------------
// Kernel 6: w3_ln_mfma — out = LN(att + h2 @ W3 + b3), written to [S,B,128] f32.
// ---------------------------------------------------------------------------
__global__ __launch_bounds__(256) void w3_ln_mfma(
    const ushort* __restrict__ h2, const ushort* __restrict__ W3T,
    const float* __restrict__ b3, const float* __restrict__ att,
    const float* __restrict__ gamma, const float* __restrict__ beta,
    float* __restrict__ out) {
    const int lane = threadIdx.x & 63;
    const int w = threadIdx.x >> 6;
    const int qi = lane & 15, g = lane >> 4;
    const int tok = (blockIdx.x * 4 + w) * 16 + qi;

    f32x4 acc[8];
#pragma unroll
    for (int f = 0; f < 8; ++f) acc[f] = (f32x4){0.f, 0.f, 0.f, 0.f};

    const ushort* bptr = h2 + (size_t)tok * FF + g * 8;
    const ushort* aptr = W3T + (size_t)qi * FF + g * 8;
#pragma unroll 4
    for (int kk = 0; kk < FF; kk += 32) {
        s16x8 bfrag = *(const s16x8*)(bptr + kk);
#pragma unroll
        for (int f = 0; f < 8; ++f) {
            s16x8 afrag = *(const s16x8*)(aptr + (size_t)(16 * f) * FF + kk);
            acc[f] = mfma32(afrag, bfrag, acc[f]);
        }
    }

    float sum = 0.f, sumsq = 0.f;
#pragma unroll
    for (int f = 0; f < 8; ++f) {
        const int c = 16 * f + 4 * g;
        float4 bv = *(const float4*)(b3 + c);
        float4 xv = *(const float4*)(att + (size_t)tok * QD + c);
        acc[f][0] += bv.x + xv.x;
        acc[f][1] += bv.y + xv.y;
        acc[f][2] += bv.z + xv.z;
        acc[f][3] += bv.w + xv.w;
#pragma unroll
        for (int r = 0; r < 4; ++r) { sum += acc[f][r]; sumsq += acc[f][r] * acc[f][r]; }
    }
    sum += __shfl_xor(sum, 16, 64);
    sum += __shfl_xor(sum, 32, 64);
    sumsq += __shfl_xor(sumsq, 16, 64);
    sumsq += __shfl_xor(sumsq, 32, 64);
    const float mu = sum * (1.0f / QD);
    const float var = sumsq * (1.0f / QD) - mu * mu;
    const float rstd = rsqrtf(var + EPS);

    const int b = tok >> 10, s = tok & 1023;
    float* orow = out + (size_t)(s * BATCH + b) * QD;
#pragma unroll
    for (int f = 0; f < 8; ++f) {
        const int c = 16 * f + 4 * g;
        float4 gm = *(const float4*)(gamma + c);
        float4 bt = *(const float4*)(beta + c);
        float4 ov;
        ov.x = (acc[f][0] - mu) * rstd * gm.x + bt.x;
        ov.y = (acc[f][1] - mu) * rstd * gm.y + bt.y;
        ov.z = (acc[f][2] - mu) * rstd * gm.z + bt.z;
        ov.w = (acc[f][3] - mu) * rstd * gm.w + bt.w;
        *(float4*)(orow + c) = ov;
    }
}

extern "C" void kernel_launch(void* const* d_in, const int* in_sizes, int n_in,
                              void* d_out, int out_size, void* d_ws, size_t ws_size,
                              hipStream_t stream) {
    const float* seq = (const float*)d_in[0];
    const float* Wq = (const float*)d_in[1];
    const float* bq = (const float*)d_in[2];
    const float* Wk = (const float*)d_in[3];
    const float* bk = (const float*)d_in[4];
    const float* Wv = (const float*)d_in[5];
    const float* bv = (const float*)d_in[6];
    const float* Wo = (const float*)d_in[7];
    const float* bo = (const float*)d_in[8];
    const float* gamma = (const float*)d_in[9];
    const float* beta = (const float*)d_in[10];
    const float* W1 = (const float*)d_in[11];
    const float* b1 = (const float*)d_in[12];
    const float* W2 = (const float*)d_in[13];
    const float* b2 = (const float*)d_in[14];
    const float* W3 = (const float*)d_in[15];
    const float* b3 = (const float*)d_in[16];

    char* wsb = (char*)d_ws;
    ushort* q_bf  = (ushort*)(wsb);                    // [0, 8 MB)
    ushort* k_bf  = (ushort*)(wsb + (8ull << 20));     // [8, 16)
    ushort* vT    = (ushort*)(wsb + (16ull << 20));    // [16, 24)
    ushort* o_bf  = (ushort*)(wsb + (24ull << 20));    // [24, 32)
    float*  att   = (float*)(wsb + (32ull << 20));     // [32, 40)
    ushort* att_bf= (ushort*)(wsb + (40ull << 20));    // [40, 44)
    ushort* h1_bf = (ushort*)(wsb);                    // [0, 16) after attn
    ushort* h2_bf = (ushort*)(wsb + (16ull << 20));    // [16, 32) after wo_ln
    ushort* WoT   = (ushort*)(wsb + (44ull << 20));
    ushort* W1T   = WoT + 32768;
    ushort* W2T   = W1T + 65536;
    ushort* W3T   = W2T + 262144;
    float* out = (float*)d_out;

    prep_weights<<<1664, 256, 0, stream>>>(Wo, W1, W2, W3, WoT, W1T, W2T, W3T);
    qkv_proj<<<NROWS / 8, 256, 0, stream>>>(seq, Wq, bq, Wk, bk, Wv, bv, q_bf, k_bf, vT);
    attn_mfma<<<(BATCH * NH) * 16, 256, 0, stream>>>(q_bf, k_bf, vT, o_bf);
    wo_ln_mfma<<<NROWS / 64, 256, 0, stream>>>(o_bf, WoT, bo, seq, gamma, beta, att, att_bf);
    ffn_mfma<QD><<<dim3(NROWS / 64, 4), 256, 0, stream>>>(att_bf, W1T, b1, h1_bf, FF);
    ffn_mfma<FF><<<dim3(NROWS / 64, 4), 256, 0, stream>>>(h1_bf, W2T, b2, h2_bf, FF);
    w3_ln_mfma<<<NROWS / 64, 256, 0, stream>>>(h2_bf, W3T, b3, att, gamma, beta, out);
}

// Round 5
// 290.622 us; speedup vs baseline: 7.0807x; 1.3325x over previous
//
#include <hip/hip_runtime.h>
#include <hip/hip_bf16.h>

#define S_LEN 1024
#define BATCH 16
#define QD 128
#define NH 8
#define HD 32
#define FF 512
#define NROWS (BATCH * S_LEN)  // 16384 token rows
#define EPS 1e-5f

typedef __attribute__((ext_vector_type(4))) float f32x4;
typedef __attribute__((ext_vector_type(8))) short s16x8;
typedef __attribute__((ext_vector_type(4))) short s16x4;

__device__ __forceinline__ ushort f2bfu(float f) {
    union { float f; unsigned u; } v; v.f = f;
    unsigned r = (v.u + 0x7FFFu + ((v.u >> 16) & 1u)) >> 16;  // RNE
    return (ushort)r;
}

__device__ __forceinline__ float exp2_fast(float x) {
#if __has_builtin(__builtin_amdgcn_exp2f)
    return __builtin_amdgcn_exp2f(x);
#else
    float r;
    asm("v_exp_f32 %0, %1" : "=v"(r) : "v"(x));
    return r;
#endif
}

__device__ __forceinline__ unsigned pk_bf16(float a, float b) {
    union { __hip_bfloat162 h; unsigned u; } c;
    c.h = __float22bfloat162_rn(make_float2(a, b));
    return c.u;
}

static __device__ __forceinline__ f32x4 mfma16(s16x4 a, s16x4 b, f32x4 c) {
#if __has_builtin(__builtin_amdgcn_mfma_f32_16x16x16bf16_1k)
    return __builtin_amdgcn_mfma_f32_16x16x16bf16_1k(a, b, c, 0, 0, 0);
#else
    asm volatile("v_mfma_f32_16x16x16_bf16 %0, %1, %2, %0" : "+v"(c) : "v"(a), "v"(b));
    return c;
#endif
}

static __device__ __forceinline__ f32x4 mfma32(s16x8 a, s16x8 b, f32x4 c) {
    return __builtin_amdgcn_mfma_f32_16x16x32_bf16(a, b, c, 0, 0, 0);
}

__device__ __forceinline__ void gl_lds16(const void* g, void* l) {
    __builtin_amdgcn_global_load_lds(
        (const __attribute__((address_space(1))) void*)g,
        (__attribute__((address_space(3))) void*)l, 16, 0, 0);
}

// ---------------------------------------------------------------------------
// Kernel 0: weight prep — bf16 transposed copies (WT[n][k] = W[k][n]).
// ---------------------------------------------------------------------------
__global__ __launch_bounds__(256) void prep_weights(
    const float* __restrict__ Wo, const float* __restrict__ W1,
    const float* __restrict__ W2, const float* __restrict__ W3,
    ushort* __restrict__ WoT, ushort* __restrict__ W1T,
    ushort* __restrict__ W2T, ushort* __restrict__ W3T) {
    int idx = blockIdx.x * 256 + threadIdx.x;
    if (idx < 32768) {
        int n = idx >> 8, k = idx & 255;
        WoT[n * 256 + k] = f2bfu(Wo[k * 128 + n]);
    } else if (idx < 98304) {
        int i = idx - 32768; int n = i >> 7, k = i & 127;
        W1T[n * 128 + k] = f2bfu(W1[k * 512 + n]);
    } else if (idx < 360448) {
        int i = idx - 98304; int n = i >> 9, k = i & 511;
        W2T[n * 512 + k] = f2bfu(W2[k * 512 + n]);
    } else {
        int i = idx - 360448; int n = i >> 9, k = i & 511;
        W3T[n * 512 + k] = f2bfu(W3[k * 128 + n]);
    }
}

// ---------------------------------------------------------------------------
// Kernel 1: fused Q/K/V projection -> bf16 outputs for MFMA attention.
// q_bf pre-scaled by log2(e)/sqrt(32)  (attention works in exp2 domain)
// ---------------------------------------------------------------------------
__global__ __launch_bounds__(256) void qkv_proj(
    const float* __restrict__ seq,
    const float* __restrict__ Wq, const float* __restrict__ bq,
    const float* __restrict__ Wk, const float* __restrict__ bk,
    const float* __restrict__ Wv, const float* __restrict__ bv,
    ushort* __restrict__ q_bf, ushort* __restrict__ k_bf, ushort* __restrict__ vT) {
    __shared__ float xs[8][QD];
    const int r0 = blockIdx.x * 8;
    const int tid = threadIdx.x;
    for (int e = tid; e < 8 * QD; e += 256) {
        int r = e >> 7, c = e & 127;
        int g = r0 + r;
        int b = g >> 10, s = g & 1023;
        xs[r][c] = seq[(s * BATCH + b) * QD + c];
    }
    __syncthreads();
    const int h = tid >> 5, d = tid & 31;
    float aq[8], ak[8], av[8];
#pragma unroll
    for (int r = 0; r < 8; ++r) { aq[r] = 0.f; ak[r] = 0.f; av[r] = 0.f; }
    const float* wq = Wq + h * QD * HD + d;
    const float* wk = Wk + h * QD * HD + d;
    const float* wv = Wv + h * QD * HD + d;
    for (int c = 0; c < QD; ++c) {
        float wqv = wq[c * HD], wkv = wk[c * HD], wvv = wv[c * HD];
#pragma unroll
        for (int r = 0; r < 8; ++r) {
            float x = xs[r][c];
            aq[r] += x * wqv;
            ak[r] += x * wkv;
            av[r] += x * wvv;
        }
    }
    const float bqv = bq[h * HD + d], bkv = bk[h * HD + d], bvv = bv[h * HD + d];
    const float SCALE = 0.25503491f;  // log2(e)/sqrt(32)
    const int b = r0 >> 10, s0 = r0 & 1023;
    const int bh = b * NH + h;
    s16x8 pv;
#pragma unroll
    for (int r = 0; r < 8; ++r) {
        size_t idx = ((size_t)bh * S_LEN + (s0 + r)) * HD + d;
        q_bf[idx] = f2bfu((aq[r] + bqv) * SCALE);
        k_bf[idx] = f2bfu(ak[r] + bkv);
        pv[r] = (short)f2bfu(av[r] + bvv);
    }
    *(s16x8*)(vT + ((size_t)bh * HD + d) * S_LEN + s0) = pv;
}

// ---------------------------------------------------------------------------
// Kernel 2: flash-style MFMA attention with LDS-staged K/V shared by 4 waves.
// Block: 256 threads = 4 waves x 16 queries = 64 queries of one bh.
// Per KBLK=64 tile: K (64x32 bf16, 4KB) + V^T (32x64, 4KB) staged via
// global_load_lds (linear dest, inverse-XOR-swizzled source), double-buffered
// with counted vmcnt(2) + raw s_barrier. Frag reads: swizzled ds_read.
// ---------------------------------------------------------------------------
__global__ __launch_bounds__(256) void attn_mfma(
    const ushort* __restrict__ qb, const ushort* __restrict__ kb,
    const ushort* __restrict__ vtb, ushort* __restrict__ o_bf) {
    __shared__ __align__(16) char lds[2][8192];  // [buf][K 4KB | V 4KB]
    const int tid = threadIdx.x;
    const int w = tid >> 6, lane = tid & 63;
    const int g = lane >> 4, qi = lane & 15;
    // XCD-aware swizzle (2048 blocks, 8 XCDs): 16 blocks of one bh per XCD
    const int bid = blockIdx.x;
    const int swz = (bid & 7) * 256 + (bid >> 3);
    const int bh = swz >> 4;
    const int qtile = (swz & 15) * 4 + w;

    const ushort* Kb = kb + (size_t)bh * S_LEN * HD;
    const ushort* VTb = vtb + (size_t)bh * HD * S_LEN;
    const s16x8 qf = *(const s16x8*)(qb + ((size_t)bh * S_LEN + qtile * 16 + qi) * HD + g * 8);

    // staging thread roles (256 threads): K row t>>2 chunk16 t&3 | V row t>>3 chunk16 t&7
    const int krow = tid >> 2;
    const int ksw = (tid & 3) ^ ((tid >> 3) & 3);   // inverse-swizzled K chunk16
    const int vrow = tid >> 3;
    const int vsw = (tid & 7) ^ ((tid >> 4) & 7);   // inverse-swizzled V chunk16
    const int wave_off = w * 1024;                   // wave-uniform LDS dest base

#define STAGE(bufp, k0)                                                          \
    do {                                                                         \
        gl_lds16(Kb + (size_t)((k0) + krow) * HD + ksw * 8, (bufp) + wave_off);  \
        gl_lds16(VTb + (size_t)vrow * S_LEN + (k0) + vsw * 8,                    \
                 (bufp) + 4096 + wave_off);                                      \
    } while (0)

    f32x4 ot0 = {0.f, 0.f, 0.f, 0.f};
    f32x4 ot1 = {0.f, 0.f, 0.f, 0.f};
    float m_run = -1e30f, l_run = 0.f;
    const f32x4 zero = {0.f, 0.f, 0.f, 0.f};

    const int koff = (g ^ ((qi >> 1) & 3)) * 16;  // swizzled K read chunk16 (bytes)
    const int vs = (qi >> 1) & 7;                 // V read swizzle

    STAGE(lds[0], 0);
    int cur = 0;
#pragma unroll 1
    for (int t = 0; t < 16; ++t) {
        if (t < 15) {
            STAGE(lds[cur ^ 1], (t + 1) * 64);
            asm volatile("s_waitcnt vmcnt(2)" ::: "memory");
        } else {
            asm volatile("s_waitcnt vmcnt(0)" ::: "memory");
        }
        __builtin_amdgcn_sched_barrier(0);
        __builtin_amdgcn_s_barrier();
        __builtin_amdgcn_sched_barrier(0);

        const char* kl = lds[cur];
        const char* vl = lds[cur] + 4096;
        s16x8 ka[4];
#pragma unroll
        for (int kt = 0; kt < 4; ++kt)
            ka[kt] = *(const s16x8*)(kl + (16 * kt + qi) * 64 + koff);
        s16x4 va[2][4];
#pragma unroll
        for (int h = 0; h < 2; ++h)
#pragma unroll
            for (int kt = 0; kt < 4; ++kt) {
                int c8 = 4 * kt + g;
                va[h][kt] = *(const s16x4*)(vl + (16 * h + qi) * 128 +
                                            (((c8 >> 1) ^ vs) * 16) + (c8 & 1) * 8);
            }

        f32x4 st[4];
        __builtin_amdgcn_s_setprio(1);
#pragma unroll
        for (int kt = 0; kt < 4; ++kt) st[kt] = mfma32(ka[kt], qf, zero);
        __builtin_amdgcn_s_setprio(0);

        float a0 = fmaxf(fmaxf(st[0][0], st[0][1]), fmaxf(st[0][2], st[0][3]));
        float a1 = fmaxf(fmaxf(st[1][0], st[1][1]), fmaxf(st[1][2], st[1][3]));
        float a2 = fmaxf(fmaxf(st[2][0], st[2][1]), fmaxf(st[2][2], st[2][3]));
        float a3 = fmaxf(fmaxf(st[3][0], st[3][1]), fmaxf(st[3][2], st[3][3]));
        float pmax = fmaxf(fmaxf(a0, a1), fmaxf(a2, a3));

        if (!__all(pmax <= m_run + 8.0f)) {  // defer-max (log2 units)
            float mt = pmax;
            mt = fmaxf(mt, __shfl_xor(mt, 16, 64));
            mt = fmaxf(mt, __shfl_xor(mt, 32, 64));
            float m_new = fmaxf(m_run, mt);
            float alpha = exp2_fast(m_run - m_new);
            l_run *= alpha;
#pragma unroll
            for (int r = 0; r < 4; ++r) { ot0[r] *= alpha; ot1[r] *= alpha; }
            m_run = m_new;
        }

        float p[4][4];
#pragma unroll
        for (int kt = 0; kt < 4; ++kt)
#pragma unroll
            for (int r = 0; r < 4; ++r) p[kt][r] = exp2_fast(st[kt][r] - m_run);
        float s0 = (p[0][0] + p[0][1]) + (p[0][2] + p[0][3]);
        float s1 = (p[1][0] + p[1][1]) + (p[1][2] + p[1][3]);
        float s2 = (p[2][0] + p[2][1]) + (p[2][2] + p[2][3]);
        float s3 = (p[3][0] + p[3][1]) + (p[3][2] + p[3][3]);
        l_run += (s0 + s1) + (s2 + s3);

        union { s16x4 v; uint2 u; } pb[4];
#pragma unroll
        for (int kt = 0; kt < 4; ++kt) {
            pb[kt].u.x = pk_bf16(p[kt][0], p[kt][1]);
            pb[kt].u.y = pk_bf16(p[kt][2], p[kt][3]);
        }
        __builtin_amdgcn_s_setprio(1);
#pragma unroll
        for (int kt = 0; kt < 4; ++kt) {
            ot0 = mfma16(va[0][kt], pb[kt].v, ot0);
            ot1 = mfma16(va[1][kt], pb[kt].v, ot1);
        }
        __builtin_amdgcn_s_setprio(0);

        __builtin_amdgcn_sched_barrier(0);
        __builtin_amdgcn_s_barrier();
        __builtin_amdgcn_sched_barrier(0);
        cur ^= 1;
    }
#undef STAGE

    l_run += __shfl_xor(l_run, 16, 64);
    l_run += __shfl_xor(l_run, 32, 64);
    const float inv_l = 1.0f / l_run;
    const int b = bh >> 3, head = bh & 7;
    const int qg = qtile * 16 + qi;
    ushort* orow = o_bf + ((size_t)(b * S_LEN + qg)) * (NH * HD) + head * HD;
    ushort4 ob0 = {f2bfu(ot0[0] * inv_l), f2bfu(ot0[1] * inv_l),
                   f2bfu(ot0[2] * inv_l), f2bfu(ot0[3] * inv_l)};
    ushort4 ob1 = {f2bfu(ot1[0] * inv_l), f2bfu(ot1[1] * inv_l),
                   f2bfu(ot1[2] * inv_l), f2bfu(ot1[3] * inv_l)};
    *(ushort4*)(orow + g * 4) = ob0;
    *(ushort4*)(orow + 16 + g * 4) = ob1;
}

// ---------------------------------------------------------------------------
// Kernel 3: wo_ln_mfma — att = LN(x + o @ Wo + bo); emits f32 + bf16 copies.
// ---------------------------------------------------------------------------
__global__ __launch_bounds__(256) void wo_ln_mfma(
    const ushort* __restrict__ o_bf, const ushort* __restrict__ WoT,
    const float* __restrict__ bo, const float* __restrict__ seq,
    const float* __restrict__ gamma, const float* __restrict__ beta,
    float* __restrict__ att, ushort* __restrict__ att_bf) {
    const int lane = threadIdx.x & 63;
    const int w = threadIdx.x >> 6;
    const int qi = lane & 15, g = lane >> 4;
    const int tok = (blockIdx.x * 4 + w) * 16 + qi;

    f32x4 acc[8];
#pragma unroll
    for (int f = 0; f < 8; ++f) acc[f] = (f32x4){0.f, 0.f, 0.f, 0.f};

    const ushort* bptr = o_bf + (size_t)tok * 256 + g * 8;
    const ushort* aptr = WoT + (size_t)qi * 256 + g * 8;
#pragma unroll 4
    for (int kk = 0; kk < 256; kk += 32) {
        s16x8 bfrag = *(const s16x8*)(bptr + kk);
#pragma unroll
        for (int f = 0; f < 8; ++f) {
            s16x8 afrag = *(const s16x8*)(aptr + (size_t)(16 * f) * 256 + kk);
            acc[f] = mfma32(afrag, bfrag, acc[f]);
        }
    }

    const int b = tok >> 10, s = tok & 1023;
    const float* xrow = seq + (size_t)(s * BATCH + b) * QD;
    float sum = 0.f, sumsq = 0.f;
#pragma unroll
    for (int f = 0; f < 8; ++f) {
        const int c = 16 * f + 4 * g;
        float4 bv = *(const float4*)(bo + c);
        float4 xv = *(const float4*)(xrow + c);
        acc[f][0] += bv.x + xv.x;
        acc[f][1] += bv.y + xv.y;
        acc[f][2] += bv.z + xv.z;
        acc[f][3] += bv.w + xv.w;
#pragma unroll
        for (int r = 0; r < 4; ++r) { sum += acc[f][r]; sumsq += acc[f][r] * acc[f][r]; }
    }
    sum += __shfl_xor(sum, 16, 64);
    sum += __shfl_xor(sum, 32, 64);
    sumsq += __shfl_xor(sumsq, 16, 64);
    sumsq += __shfl_xor(sumsq, 32, 64);
    const float mu = sum * (1.0f / QD);
    const float var = sumsq * (1.0f / QD) - mu * mu;
    const float rstd = rsqrtf(var + EPS);

#pragma unroll
    for (int f = 0; f < 8; ++f) {
        const int c = 16 * f + 4 * g;
        float4 gm = *(const float4*)(gamma + c);
        float4 bt = *(const float4*)(beta + c);
        float4 ov;
        ov.x = (acc[f][0] - mu) * rstd * gm.x + bt.x;
        ov.y = (acc[f][1] - mu) * rstd * gm.y + bt.y;
        ov.z = (acc[f][2] - mu) * rstd * gm.z + bt.z;
        ov.w = (acc[f][3] - mu) * rstd * gm.w + bt.w;
        *(float4*)(att + (size_t)tok * QD + c) = ov;
        ushort4 pv = {f2bfu(ov.x), f2bfu(ov.y), f2bfu(ov.z), f2bfu(ov.w)};
        *(ushort4*)(att_bf + (size_t)tok * QD + c) = pv;
    }
}

// ---------------------------------------------------------------------------
// Kernel 4/5: ffn_mfma — out_bf = relu(act_bf @ WT^T + bias).
// ---------------------------------------------------------------------------
template <int K>
__global__ __launch_bounds__(256) void ffn_mfma(
    const ushort* __restrict__ act, const ushort* __restrict__ WT,
    const float* __restrict__ bias, ushort* __restrict__ out, int N) {
    const int lane = threadIdx.x & 63;
    const int w = threadIdx.x >> 6;
    const int qi = lane & 15, g = lane >> 4;
    const int tok = (blockIdx.x * 4 + w) * 16 + qi;
    const int n0 = blockIdx.y * 128;

    f32x4 acc[8];
#pragma unroll
    for (int f = 0; f < 8; ++f) acc[f] = (f32x4){0.f, 0.f, 0.f, 0.f};

    const ushort* bptr = act + (size_t)tok * K + g * 8;
    const ushort* aptr = WT + (size_t)(n0 + qi) * K + g * 8;
#pragma unroll 4
    for (int kk = 0; kk < K; kk += 32) {
        s16x8 bfrag = *(const s16x8*)(bptr + kk);
#pragma unroll
        for (int f = 0; f < 8; ++f) {
            s16x8 afrag = *(const s16x8*)(aptr + (size_t)(16 * f) * K + kk);
            acc[f] = mfma32(afrag, bfrag, acc[f]);
        }
    }
#pragma unroll
    for (int f = 0; f < 8; ++f) {
        const int c = n0 + 16 * f + 4 * g;
        float4 bv = *(const float4*)(bias + c);
        ushort4 pv;
        pv.x = f2bfu(fmaxf(acc[f][0] + bv.x, 0.f));
        pv.y = f2bfu(fmaxf(acc[f][1] + bv.y, 0.f));
        pv.z = f2bfu(fmaxf(acc[f][2] + bv.z, 0.f));
        pv.w = f2bfu(fmaxf(acc[f][3] + bv.w, 0.f));
        *(ushort4*)(out + (size_t)tok * N + c) = pv;
    }
}

// ---------------------------------------------------------------------------
// Kernel 6: w3_ln_mfma — out = LN(att + h2 @ W3 + b3), written to [S,B,128] f32.
// ---------------------------------------------------------------------------
__global__ __launch_bounds__(256) void w3_ln_mfma(
    const ushort* __restrict__ h2, const ushort* __restrict__ W3T,
    const float* __restrict__ b3, const float* __restrict__ att,
    const float* __restrict__ gamma, const float* __restrict__ beta,
    float* __restrict__ out) {
    const int lane = threadIdx.x & 63;
    const int w = threadIdx.x >> 6;
    const int qi = lane & 15, g = lane >> 4;
    const int tok = (blockIdx.x * 4 + w) * 16 + qi;

    f32x4 acc[8];
#pragma unroll
    for (int f = 0; f < 8; ++f) acc[f] = (f32x4){0.f, 0.f, 0.f, 0.f};

    const ushort* bptr = h2 + (size_t)tok * FF + g * 8;
    const ushort* aptr = W3T + (size_t)qi * FF + g * 8;
#pragma unroll 4
    for (int kk = 0; kk < FF; kk += 32) {
        s16x8 bfrag = *(const s16x8*)(bptr + kk);
#pragma unroll
        for (int f = 0; f < 8; ++f) {
            s16x8 afrag = *(const s16x8*)(aptr + (size_t)(16 * f) * FF + kk);
            acc[f] = mfma32(afrag, bfrag, acc[f]);
        }
    }

    float sum = 0.f, sumsq = 0.f;
#pragma unroll
    for (int f = 0; f < 8; ++f) {
        const int c = 16 * f + 4 * g;
        float4 bv = *(const float4*)(b3 + c);
        float4 xv = *(const float4*)(att + (size_t)tok * QD + c);
        acc[f][0] += bv.x + xv.x;
        acc[f][1] += bv.y + xv.y;
        acc[f][2] += bv.z + xv.z;
        acc[f][3] += bv.w + xv.w;
#pragma unroll
        for (int r = 0; r < 4; ++r) { sum += acc[f][r]; sumsq += acc[f][r] * acc[f][r]; }
    }
    sum += __shfl_xor(sum, 16, 64);
    sum += __shfl_xor(sum, 32, 64);
    sumsq += __shfl_xor(sumsq, 16, 64);
    sumsq += __shfl_xor(sumsq, 32, 64);
    const float mu = sum * (1.0f / QD);
    const float var = sumsq * (1.0f / QD) - mu * mu;
    const float rstd = rsqrtf(var + EPS);

    const int b = tok >> 10, s = tok & 1023;
    float* orow = out + (size_t)(s * BATCH + b) * QD;
#pragma unroll
    for (int f = 0; f < 8; ++f) {
        const int c = 16 * f + 4 * g;
        float4 gm = *(const float4*)(gamma + c);
        float4 bt = *(const float4*)(beta + c);
        float4 ov;
        ov.x = (acc[f][0] - mu) * rstd * gm.x + bt.x;
        ov.y = (acc[f][1] - mu) * rstd * gm.y + bt.y;
        ov.z = (acc[f][2] - mu) * rstd * gm.z + bt.z;
        ov.w = (acc[f][3] - mu) * rstd * gm.w + bt.w;
        *(float4*)(orow + c) = ov;
    }
}

extern "C" void kernel_launch(void* const* d_in, const int* in_sizes, int n_in,
                              void* d_out, int out_size, void* d_ws, size_t ws_size,
                              hipStream_t stream) {
    const float* seq = (const float*)d_in[0];
    const float* Wq = (const float*)d_in[1];
    const float* bq = (const float*)d_in[2];
    const float* Wk = (const float*)d_in[3];
    const float* bk = (const float*)d_in[4];
    const float* Wv = (const float*)d_in[5];
    const float* bv = (const float*)d_in[6];
    const float* Wo = (const float*)d_in[7];
    const float* bo = (const float*)d_in[8];
    const float* gamma = (const float*)d_in[9];
    const float* beta = (const float*)d_in[10];
    const float* W1 = (const float*)d_in[11];
    const float* b1 = (const float*)d_in[12];
    const float* W2 = (const float*)d_in[13];
    const float* b2 = (const float*)d_in[14];
    const float* W3 = (const float*)d_in[15];
    const float* b3 = (const float*)d_in[16];

    char* wsb = (char*)d_ws;
    ushort* q_bf  = (ushort*)(wsb);                    // [0, 8 MB)
    ushort* k_bf  = (ushort*)(wsb + (8ull << 20));     // [8, 16)
    ushort* vT    = (ushort*)(wsb + (16ull << 20));    // [16, 24)
    ushort* o_bf  = (ushort*)(wsb + (24ull << 20));    // [24, 32)
    float*  att   = (float*)(wsb + (32ull << 20));     // [32, 40)
    ushort* att_bf= (ushort*)(wsb + (40ull << 20));    // [40, 44)
    ushort* h1_bf = (ushort*)(wsb);                    // [0, 16) after attn
    ushort* h2_bf = (ushort*)(wsb + (16ull << 20));    // [16, 32) after wo_ln
    ushort* WoT   = (ushort*)(wsb + (44ull << 20));
    ushort* W1T   = WoT + 32768;
    ushort* W2T   = W1T + 65536;
    ushort* W3T   = W2T + 262144;
    float* out = (float*)d_out;

    prep_weights<<<1664, 256, 0, stream>>>(Wo, W1, W2, W3, WoT, W1T, W2T, W3T);
    qkv_proj<<<NROWS / 8, 256, 0, stream>>>(seq, Wq, bq, Wk, bk, Wv, bv, q_bf, k_bf, vT);
    attn_mfma<<<(BATCH * NH) * 16, 256, 0, stream>>>(q_bf, k_bf, vT, o_bf);
    wo_ln_mfma<<<NROWS / 64, 256, 0, stream>>>(o_bf, WoT, bo, seq, gamma, beta, att, att_bf);
    ffn_mfma<QD><<<dim3(NROWS / 64, 4), 256, 0, stream>>>(att_bf, W1T, b1, h1_bf, FF);
    ffn_mfma<FF><<<dim3(NROWS / 64, 4), 256, 0, stream>>>(h1_bf, W2T, b2, h2_bf, FF);
    w3_ln_mfma<<<NROWS / 64, 256, 0, stream>>>(h2_bf, W3T, b3, att, gamma, beta, out);
}

// Round 6
// 230.146 us; speedup vs baseline: 8.9414x; 1.2628x over previous
//
#include <hip/hip_runtime.h>
#include <hip/hip_bf16.h>

#define S_LEN 1024
#define BATCH 16
#define QD 128
#define NH 8
#define HD 32
#define FF 512
#define NROWS (BATCH * S_LEN)  // 16384 token rows
#define EPS 1e-5f

typedef __attribute__((ext_vector_type(4))) float f32x4;
typedef __attribute__((ext_vector_type(8))) short s16x8;
typedef __attribute__((ext_vector_type(4))) short s16x4;

__device__ __forceinline__ ushort f2bfu(float f) {
    union { float f; unsigned u; } v; v.f = f;
    unsigned r = (v.u + 0x7FFFu + ((v.u >> 16) & 1u)) >> 16;  // RNE
    return (ushort)r;
}

__device__ __forceinline__ float exp2_fast(float x) {
#if __has_builtin(__builtin_amdgcn_exp2f)
    return __builtin_amdgcn_exp2f(x);
#else
    float r;
    asm("v_exp_f32 %0, %1" : "=v"(r) : "v"(x));
    return r;
#endif
}

__device__ __forceinline__ unsigned pk_bf16(float a, float b) {
    union { __hip_bfloat162 h; unsigned u; } c;
    c.h = __float22bfloat162_rn(make_float2(a, b));
    return c.u;
}

static __device__ __forceinline__ f32x4 mfma16(s16x4 a, s16x4 b, f32x4 c) {
#if __has_builtin(__builtin_amdgcn_mfma_f32_16x16x16bf16_1k)
    return __builtin_amdgcn_mfma_f32_16x16x16bf16_1k(a, b, c, 0, 0, 0);
#else
    asm volatile("v_mfma_f32_16x16x16_bf16 %0, %1, %2, %0" : "+v"(c) : "v"(a), "v"(b));
    return c;
#endif
}

static __device__ __forceinline__ f32x4 mfma32(s16x8 a, s16x8 b, f32x4 c) {
    return __builtin_amdgcn_mfma_f32_16x16x32_bf16(a, b, c, 0, 0, 0);
}

__device__ __forceinline__ void gl_lds16(const void* g, void* l) {
    __builtin_amdgcn_global_load_lds(
        (const __attribute__((address_space(1))) void*)g,
        (__attribute__((address_space(3))) void*)l, 16, 0, 0);
}

// ---------------------------------------------------------------------------
// Kernel 0: weight prep — bf16 transposed copies.
// WoT 128x256 | W1T 512x128 | W2T 512x512 | W3T 128x512 | WqkvT 768x128
// total 524288 elements = 2048 * 256
// ---------------------------------------------------------------------------
__global__ __launch_bounds__(256) void prep_weights(
    const float* __restrict__ Wo, const float* __restrict__ W1,
    const float* __restrict__ W2, const float* __restrict__ W3,
    const float* __restrict__ Wq, const float* __restrict__ Wk,
    const float* __restrict__ Wv,
    ushort* __restrict__ WoT, ushort* __restrict__ W1T,
    ushort* __restrict__ W2T, ushort* __restrict__ W3T,
    ushort* __restrict__ WqkvT) {
    int idx = blockIdx.x * 256 + threadIdx.x;
    if (idx < 32768) {
        int n = idx >> 8, k = idx & 255;
        WoT[n * 256 + k] = f2bfu(Wo[k * 128 + n]);
    } else if (idx < 98304) {
        int i = idx - 32768; int n = i >> 7, k = i & 127;
        W1T[n * 128 + k] = f2bfu(W1[k * 512 + n]);
    } else if (idx < 360448) {
        int i = idx - 98304; int n = i >> 9, k = i & 511;
        W2T[n * 512 + k] = f2bfu(W2[k * 512 + n]);
    } else if (idx < 425984) {
        int i = idx - 360448; int n = i >> 9, k = i & 511;
        W3T[n * 512 + k] = f2bfu(W3[k * 128 + n]);
    } else {
        int i = idx - 425984;            // 0..98303
        int n = i >> 7, k = i & 127;     // n = p*256 + h*32 + d
        int p = n >> 8, h = (n >> 5) & 7, d = n & 31;
        const float* W = (p == 0) ? Wq : (p == 1) ? Wk : Wv;
        WqkvT[n * 128 + k] = f2bfu(W[(h * QD + k) * HD + d]);
    }
}

// ---------------------------------------------------------------------------
// Kernel 1a: seq f32 [S,B,128] -> x_bf bf16 token-major [b*1024+s][128]
// ---------------------------------------------------------------------------
__global__ __launch_bounds__(256) void seq2bf(
    const float* __restrict__ seq, ushort* __restrict__ x_bf) {
    int t = blockIdx.x * 256 + threadIdx.x;
    int e4 = t * 4;
    int s = e4 >> 11, b = (e4 >> 7) & 15, c = e4 & 127;
    float4 v = *(const float4*)(seq + e4);
    ushort4 o = {f2bfu(v.x), f2bfu(v.y), f2bfu(v.z), f2bfu(v.w)};
    *(ushort4*)(x_bf + ((size_t)(b * 1024 + s)) * 128 + c) = o;
}

// ---------------------------------------------------------------------------
// Kernel 1b: qkv_mfma — swapped-MFMA GEMM [16384 x 768 x 128].
// Wave: 16 tokens x 128 n. n = proj*256 + h*32 + d (uniform proj per block).
// q_bf: [(b*8+h)*1024+s][32] scaled by log2(e)/sqrt(32); k_bf same unscaled;
// vT:   [(b*8+h)*32+d][1024]
// ---------------------------------------------------------------------------
__global__ __launch_bounds__(256) void qkv_mfma(
    const ushort* __restrict__ x_bf, const ushort* __restrict__ WqkvT,
    const float* __restrict__ bq, const float* __restrict__ bk,
    const float* __restrict__ bv,
    ushort* __restrict__ q_bf, ushort* __restrict__ k_bf,
    ushort* __restrict__ vT) {
    const int lane = threadIdx.x & 63;
    const int w = threadIdx.x >> 6;
    const int qi = lane & 15, g = lane >> 4;
    const int tok = (blockIdx.x * 4 + w) * 16 + qi;
    const int n0 = blockIdx.y * 128;

    f32x4 acc[8];
#pragma unroll
    for (int f = 0; f < 8; ++f) acc[f] = (f32x4){0.f, 0.f, 0.f, 0.f};

    const ushort* bptr = x_bf + (size_t)tok * 128 + g * 8;
    const ushort* aptr = WqkvT + (size_t)(n0 + qi) * 128 + g * 8;
#pragma unroll
    for (int kk = 0; kk < 128; kk += 32) {
        s16x8 bfrag = *(const s16x8*)(bptr + kk);
#pragma unroll
        for (int f = 0; f < 8; ++f) {
            s16x8 afrag = *(const s16x8*)(aptr + (size_t)(16 * f) * 128 + kk);
            acc[f] = mfma32(afrag, bfrag, acc[f]);
        }
    }

    const int b = tok >> 10, s = tok & 1023;
    const float SCALE = 0.25503491f;  // log2(e)/sqrt(32)
    if (n0 < 256) {
#pragma unroll
        for (int f = 0; f < 8; ++f)
#pragma unroll
            for (int r = 0; r < 4; ++r) {
                int n = n0 + 16 * f + 4 * g + r;
                int h = (n >> 5) & 7, d = n & 31;
                q_bf[((size_t)(b * 8 + h) * 1024 + s) * 32 + d] =
                    f2bfu((acc[f][r] + bq[h * 32 + d]) * SCALE);
            }
    } else if (n0 < 512) {
#pragma unroll
        for (int f = 0; f < 8; ++f)
#pragma unroll
            for (int r = 0; r < 4; ++r) {
                int n = n0 + 16 * f + 4 * g + r;
                int h = (n >> 5) & 7, d = n & 31;
                k_bf[((size_t)(b * 8 + h) * 1024 + s) * 32 + d] =
                    f2bfu(acc[f][r] + bk[h * 32 + d]);
            }
    } else {
#pragma unroll
        for (int f = 0; f < 8; ++f)
#pragma unroll
            for (int r = 0; r < 4; ++r) {
                int n = n0 + 16 * f + 4 * g + r;
                int h = (n >> 5) & 7, d = n & 31;
                vT[((size_t)(b * 8 + h) * 32 + d) * 1024 + s] =
                    f2bfu(acc[f][r] + bv[h * 32 + d]);
            }
    }
}

// ---------------------------------------------------------------------------
// Kernel 2: flash-style MFMA attention with LDS-staged K/V shared by 4 waves.
// ---------------------------------------------------------------------------
__global__ __launch_bounds__(256) void attn_mfma(
    const ushort* __restrict__ qb, const ushort* __restrict__ kb,
    const ushort* __restrict__ vtb, ushort* __restrict__ o_bf) {
    __shared__ __align__(16) char lds[2][8192];  // [buf][K 4KB | V 4KB]
    const int tid = threadIdx.x;
    const int w = tid >> 6, lane = tid & 63;
    const int g = lane >> 4, qi = lane & 15;
    const int bid = blockIdx.x;
    const int swz = (bid & 7) * 256 + (bid >> 3);
    const int bh = swz >> 4;
    const int qtile = (swz & 15) * 4 + w;

    const ushort* Kb = kb + (size_t)bh * S_LEN * HD;
    const ushort* VTb = vtb + (size_t)bh * HD * S_LEN;
    const s16x8 qf = *(const s16x8*)(qb + ((size_t)bh * S_LEN + qtile * 16 + qi) * HD + g * 8);

    const int krow = tid >> 2;
    const int ksw = (tid & 3) ^ ((tid >> 3) & 3);
    const int vrow = tid >> 3;
    const int vsw = (tid & 7) ^ ((tid >> 4) & 7);
    const int wave_off = w * 1024;

#define STAGE(bufp, k0)                                                          \
    do {                                                                         \
        gl_lds16(Kb + (size_t)((k0) + krow) * HD + ksw * 8, (bufp) + wave_off);  \
        gl_lds16(VTb + (size_t)vrow * S_LEN + (k0) + vsw * 8,                    \
                 (bufp) + 4096 + wave_off);                                      \
    } while (0)

    f32x4 ot0 = {0.f, 0.f, 0.f, 0.f};
    f32x4 ot1 = {0.f, 0.f, 0.f, 0.f};
    float m_run = -1e30f, l_run = 0.f;
    const f32x4 zero = {0.f, 0.f, 0.f, 0.f};

    const int koff = (g ^ ((qi >> 1) & 3)) * 16;
    const int vs = (qi >> 1) & 7;

    STAGE(lds[0], 0);
    int cur = 0;
#pragma unroll 1
    for (int t = 0; t < 16; ++t) {
        if (t < 15) {
            STAGE(lds[cur ^ 1], (t + 1) * 64);
            asm volatile("s_waitcnt vmcnt(2)" ::: "memory");
        } else {
            asm volatile("s_waitcnt vmcnt(0)" ::: "memory");
        }
        __builtin_amdgcn_sched_barrier(0);
        __builtin_amdgcn_s_barrier();
        __builtin_amdgcn_sched_barrier(0);

        const char* kl = lds[cur];
        const char* vl = lds[cur] + 4096;
        s16x8 ka[4];
#pragma unroll
        for (int kt = 0; kt < 4; ++kt)
            ka[kt] = *(const s16x8*)(kl + (16 * kt + qi) * 64 + koff);
        s16x4 va[2][4];
#pragma unroll
        for (int h = 0; h < 2; ++h)
#pragma unroll
            for (int kt = 0; kt < 4; ++kt) {
                int c8 = 4 * kt + g;
                va[h][kt] = *(const s16x4*)(vl + (16 * h + qi) * 128 +
                                            (((c8 >> 1) ^ vs) * 16) + (c8 & 1) * 8);
            }

        f32x4 st[4];
        __builtin_amdgcn_s_setprio(1);
#pragma unroll
        for (int kt = 0; kt < 4; ++kt) st[kt] = mfma32(ka[kt], qf, zero);
        __builtin_amdgcn_s_setprio(0);

        float a0 = fmaxf(fmaxf(st[0][0], st[0][1]), fmaxf(st[0][2], st[0][3]));
        float a1 = fmaxf(fmaxf(st[1][0], st[1][1]), fmaxf(st[1][2], st[1][3]));
        float a2 = fmaxf(fmaxf(st[2][0], st[2][1]), fmaxf(st[2][2], st[2][3]));
        float a3 = fmaxf(fmaxf(st[3][0], st[3][1]), fmaxf(st[3][2], st[3][3]));
        float pmax = fmaxf(fmaxf(a0, a1), fmaxf(a2, a3));

        if (!__all(pmax <= m_run + 8.0f)) {  // defer-max (log2 units)
            float mt = pmax;
            mt = fmaxf(mt, __shfl_xor(mt, 16, 64));
            mt = fmaxf(mt, __shfl_xor(mt, 32, 64));
            float m_new = fmaxf(m_run, mt);
            float alpha = exp2_fast(m_run - m_new);
            l_run *= alpha;
#pragma unroll
            for (int r = 0; r < 4; ++r) { ot0[r] *= alpha; ot1[r] *= alpha; }
            m_run = m_new;
        }

        float p[4][4];
#pragma unroll
        for (int kt = 0; kt < 4; ++kt)
#pragma unroll
            for (int r = 0; r < 4; ++r) p[kt][r] = exp2_fast(st[kt][r] - m_run);
        float s0 = (p[0][0] + p[0][1]) + (p[0][2] + p[0][3]);
        float s1 = (p[1][0] + p[1][1]) + (p[1][2] + p[1][3]);
        float s2 = (p[2][0] + p[2][1]) + (p[2][2] + p[2][3]);
        float s3 = (p[3][0] + p[3][1]) + (p[3][2] + p[3][3]);
        l_run += (s0 + s1) + (s2 + s3);

        union { s16x4 v; uint2 u; } pb[4];
#pragma unroll
        for (int kt = 0; kt < 4; ++kt) {
            pb[kt].u.x = pk_bf16(p[kt][0], p[kt][1]);
            pb[kt].u.y = pk_bf16(p[kt][2], p[kt][3]);
        }
        __builtin_amdgcn_s_setprio(1);
#pragma unroll
        for (int kt = 0; kt < 4; ++kt) {
            ot0 = mfma16(va[0][kt], pb[kt].v, ot0);
            ot1 = mfma16(va[1][kt], pb[kt].v, ot1);
        }
        __builtin_amdgcn_s_setprio(0);

        __builtin_amdgcn_sched_barrier(0);
        __builtin_amdgcn_s_barrier();
        __builtin_amdgcn_sched_barrier(0);
        cur ^= 1;
    }
#undef STAGE

    l_run += __shfl_xor(l_run, 16, 64);
    l_run += __shfl_xor(l_run, 32, 64);
    const float inv_l = 1.0f / l_run;
    const int b = bh >> 3, head = bh & 7;
    const int qg = qtile * 16 + qi;
    ushort* orow = o_bf + ((size_t)(b * S_LEN + qg)) * (NH * HD) + head * HD;
    ushort4 ob0 = {f2bfu(ot0[0] * inv_l), f2bfu(ot0[1] * inv_l),
                   f2bfu(ot0[2] * inv_l), f2bfu(ot0[3] * inv_l)};
    ushort4 ob1 = {f2bfu(ot1[0] * inv_l), f2bfu(ot1[1] * inv_l),
                   f2bfu(ot1[2] * inv_l), f2bfu(ot1[3] * inv_l)};
    *(ushort4*)(orow + g * 4) = ob0;
    *(ushort4*)(orow + 16 + g * 4) = ob1;
}

// ---------------------------------------------------------------------------
// Kernel 3: wo_ln_mfma — att = LN(x + o @ Wo + bo); emits f32 + bf16 copies.
// ---------------------------------------------------------------------------
__global__ __launch_bounds__(256) void wo_ln_mfma(
    const ushort* __restrict__ o_bf, const ushort* __restrict__ WoT,
    const float* __restrict__ bo, const float* __restrict__ seq,
    const float* __restrict__ gamma, const float* __restrict__ beta,
    float* __restrict__ att, ushort* __restrict__ att_bf) {
    const int lane = threadIdx.x & 63;
    const int w = threadIdx.x >> 6;
    const int qi = lane & 15, g = lane >> 4;
    const int tok = (blockIdx.x * 4 + w) * 16 + qi;

    f32x4 acc[8];
#pragma unroll
    for (int f = 0; f < 8; ++f) acc[f] = (f32x4){0.f, 0.f, 0.f, 0.f};

    const ushort* bptr = o_bf + (size_t)tok * 256 + g * 8;
    const ushort* aptr = WoT + (size_t)qi * 256 + g * 8;
#pragma unroll 4
    for (int kk = 0; kk < 256; kk += 32) {
        s16x8 bfrag = *(const s16x8*)(bptr + kk);
#pragma unroll
        for (int f = 0; f < 8; ++f) {
            s16x8 afrag = *(const s16x8*)(aptr + (size_t)(16 * f) * 256 + kk);
            acc[f] = mfma32(afrag, bfrag, acc[f]);
        }
    }

    const int b = tok >> 10, s = tok & 1023;
    const float* xrow = seq + (size_t)(s * BATCH + b) * QD;
    float sum = 0.f, sumsq = 0.f;
#pragma unroll
    for (int f = 0; f < 8; ++f) {
        const int c = 16 * f + 4 * g;
        float4 bv = *(const float4*)(bo + c);
        float4 xv = *(const float4*)(xrow + c);
        acc[f][0] += bv.x + xv.x;
        acc[f][1] += bv.y + xv.y;
        acc[f][2] += bv.z + xv.z;
        acc[f][3] += bv.w + xv.w;
#pragma unroll
        for (int r = 0; r < 4; ++r) { sum += acc[f][r]; sumsq += acc[f][r] * acc[f][r]; }
    }
    sum += __shfl_xor(sum, 16, 64);
    sum += __shfl_xor(sum, 32, 64);
    sumsq += __shfl_xor(sumsq, 16, 64);
    sumsq += __shfl_xor(sumsq, 32, 64);
    const float mu = sum * (1.0f / QD);
    const float var = sumsq * (1.0f / QD) - mu * mu;
    const float rstd = rsqrtf(var + EPS);

#pragma unroll
    for (int f = 0; f < 8; ++f) {
        const int c = 16 * f + 4 * g;
        float4 gm = *(const float4*)(gamma + c);
        float4 bt = *(const float4*)(beta + c);
        float4 ov;
        ov.x = (acc[f][0] - mu) * rstd * gm.x + bt.x;
        ov.y = (acc[f][1] - mu) * rstd * gm.y + bt.y;
        ov.z = (acc[f][2] - mu) * rstd * gm.z + bt.z;
        ov.w = (acc[f][3] - mu) * rstd * gm.w + bt.w;
        *(float4*)(att + (size_t)tok * QD + c) = ov;
        ushort4 pv = {f2bfu(ov.x), f2bfu(ov.y), f2bfu(ov.z), f2bfu(ov.w)};
        *(ushort4*)(att_bf + (size_t)tok * QD + c) = pv;
    }
}

// ---------------------------------------------------------------------------
// Kernel 4/5: ffn_mfma — out_bf = relu(act_bf @ WT^T + bias).
// ---------------------------------------------------------------------------
template <int K>
__global__ __launch_bounds__(256) void ffn_mfma(
    const ushort* __restrict__ act, const ushort* __restrict__ WT,
    const float* __restrict__ bias, ushort* __restrict__ out, int N) {
    const int lane = threadIdx.x & 63;
    const int w = threadIdx.x >> 6;
    const int qi = lane & 15, g = lane >> 4;
    const int tok = (blockIdx.x * 4 + w) * 16 + qi;
    const int n0 = blockIdx.y * 128;

    f32x4 acc[8];
#pragma unroll
    for (int f = 0; f < 8; ++f) acc[f] = (f32x4){0.f, 0.f, 0.f, 0.f};

    const ushort* bptr = act + (size_t)tok * K + g * 8;
    const ushort* aptr = WT + (size_t)(n0 + qi) * K + g * 8;
#pragma unroll 4
    for (int kk = 0; kk < K; kk += 32) {
        s16x8 bfrag = *(const s16x8*)(bptr + kk);
#pragma unroll
        for (int f = 0; f < 8; ++f) {
            s16x8 afrag = *(const s16x8*)(aptr + (size_t)(16 * f) * K + kk);
            acc[f] = mfma32(afrag, bfrag, acc[f]);
        }
    }
#pragma unroll
    for (int f = 0; f < 8; ++f) {
        const int c = n0 + 16 * f + 4 * g;
        float4 bv = *(const float4*)(bias + c);
        ushort4 pv;
        pv.x = f2bfu(fmaxf(acc[f][0] + bv.x, 0.f));
        pv.y = f2bfu(fmaxf(acc[f][1] + bv.y, 0.f));
        pv.z = f2bfu(fmaxf(acc[f][2] + bv.z, 0.f));
        pv.w = f2bfu(fmaxf(acc[f][3] + bv.w, 0.f));
        *(ushort4*)(out + (size_t)tok * N + c) = pv;
    }
}

// ---------------------------------------------------------------------------
// Kernel 6: w3_ln_mfma — out = LN(att + h2 @ W3 + b3), written to [S,B,128] f32.
// ---------------------------------------------------------------------------
__global__ __launch_bounds__(256) void w3_ln_mfma(
    const ushort* __restrict__ h2, const ushort* __restrict__ W3T,
    const float* __restrict__ b3, const float* __restrict__ att,
    const float* __restrict__ gamma, const float* __restrict__ beta,
    float* __restrict__ out) {
    const int lane = threadIdx.x & 63;
    const int w = threadIdx.x >> 6;
    const int qi = lane & 15, g = lane >> 4;
    const int tok = (blockIdx.x * 4 + w) * 16 + qi;

    f32x4 acc[8];
#pragma unroll
    for (int f = 0; f < 8; ++f) acc[f] = (f32x4){0.f, 0.f, 0.f, 0.f};

    const ushort* bptr = h2 + (size_t)tok * FF + g * 8;
    const ushort* aptr = W3T + (size_t)qi * FF + g * 8;
#pragma unroll 4
    for (int kk = 0; kk < FF; kk += 32) {
        s16x8 bfrag = *(const s16x8*)(bptr + kk);
#pragma unroll
        for (int f = 0; f < 8; ++f) {
            s16x8 afrag = *(const s16x8*)(aptr + (size_t)(16 * f) * FF + kk);
            acc[f] = mfma32(afrag, bfrag, acc[f]);
        }
    }

    float sum = 0.f, sumsq = 0.f;
#pragma unroll
    for (int f = 0; f < 8; ++f) {
        const int c = 16 * f + 4 * g;
        float4 bv = *(const float4*)(b3 + c);
        float4 xv = *(const float4*)(att + (size_t)tok * QD + c);
        acc[f][0] += bv.x + xv.x;
        acc[f][1] += bv.y + xv.y;
        acc[f][2] += bv.z + xv.z;
        acc[f][3] += bv.w + xv.w;
#pragma unroll
        for (int r = 0; r < 4; ++r) { sum += acc[f][r]; sumsq += acc[f][r] * acc[f][r]; }
    }
    sum += __shfl_xor(sum, 16, 64);
    sum += __shfl_xor(sum, 32, 64);
    sumsq += __shfl_xor(sumsq, 16, 64);
    sumsq += __shfl_xor(sumsq, 32, 64);
    const float mu = sum * (1.0f / QD);
    const float var = sumsq * (1.0f / QD) - mu * mu;
    const float rstd = rsqrtf(var + EPS);

    const int b = tok >> 10, s = tok & 1023;
    float* orow = out + (size_t)(s * BATCH + b) * QD;
#pragma unroll
    for (int f = 0; f < 8; ++f) {
        const int c = 16 * f + 4 * g;
        float4 gm = *(const float4*)(gamma + c);
        float4 bt = *(const float4*)(beta + c);
        float4 ov;
        ov.x = (acc[f][0] - mu) * rstd * gm.x + bt.x;
        ov.y = (acc[f][1] - mu) * rstd * gm.y + bt.y;
        ov.z = (acc[f][2] - mu) * rstd * gm.z + bt.z;
        ov.w = (acc[f][3] - mu) * rstd * gm.w + bt.w;
        *(float4*)(orow + c) = ov;
    }
}

extern "C" void kernel_launch(void* const* d_in, const int* in_sizes, int n_in,
                              void* d_out, int out_size, void* d_ws, size_t ws_size,
                              hipStream_t stream) {
    const float* seq = (const float*)d_in[0];
    const float* Wq = (const float*)d_in[1];
    const float* bq = (const float*)d_in[2];
    const float* Wk = (const float*)d_in[3];
    const float* bk = (const float*)d_in[4];
    const float* Wv = (const float*)d_in[5];
    const float* bv = (const float*)d_in[6];
    const float* Wo = (const float*)d_in[7];
    const float* bo = (const float*)d_in[8];
    const float* gamma = (const float*)d_in[9];
    const float* beta = (const float*)d_in[10];
    const float* W1 = (const float*)d_in[11];
    const float* b1 = (const float*)d_in[12];
    const float* W2 = (const float*)d_in[13];
    const float* b2 = (const float*)d_in[14];
    const float* W3 = (const float*)d_in[15];
    const float* b3 = (const float*)d_in[16];

    char* wsb = (char*)d_ws;
    ushort* q_bf  = (ushort*)(wsb);                    // [0, 8 MB)
    ushort* k_bf  = (ushort*)(wsb + (8ull << 20));     // [8, 16)
    ushort* vT    = (ushort*)(wsb + (16ull << 20));    // [16, 24)
    ushort* o_bf  = (ushort*)(wsb + (24ull << 20));    // [24, 32)
    float*  att   = (float*)(wsb + (32ull << 20));     // [32, 40)
    ushort* att_bf= (ushort*)(wsb + (40ull << 20));    // [40, 44)
    ushort* h1_bf = (ushort*)(wsb);                    // [0, 16) after attn
    ushort* h2_bf = (ushort*)(wsb + (16ull << 20));    // [16, 32) after wo_ln
    ushort* x_bf  = (ushort*)(wsb + (45ull << 20));    // [45, 49) 4 MB
    ushort* WoT   = (ushort*)(wsb + (49ull << 20));
    ushort* W1T   = WoT + 32768;
    ushort* W2T   = W1T + 65536;
    ushort* W3T   = W2T + 262144;
    ushort* WqkvT = W3T + 65536;                       // 768*128
    float* out = (float*)d_out;

    prep_weights<<<2048, 256, 0, stream>>>(Wo, W1, W2, W3, Wq, Wk, Wv,
                                           WoT, W1T, W2T, W3T, WqkvT);
    seq2bf<<<2048, 256, 0, stream>>>(seq, x_bf);
    qkv_mfma<<<dim3(NROWS / 64, 6), 256, 0, stream>>>(x_bf, WqkvT, bq, bk, bv,
                                                      q_bf, k_bf, vT);
    attn_mfma<<<(BATCH * NH) * 16, 256, 0, stream>>>(q_bf, k_bf, vT, o_bf);
    wo_ln_mfma<<<NROWS / 64, 256, 0, stream>>>(o_bf, WoT, bo, seq, gamma, beta, att, att_bf);
    ffn_mfma<QD><<<dim3(NROWS / 64, 4), 256, 0, stream>>>(att_bf, W1T, b1, h1_bf, FF);
    ffn_mfma<FF><<<dim3(NROWS / 64, 4), 256, 0, stream>>>(h1_bf, W2T, b2, h2_bf, FF);
    w3_ln_mfma<<<NROWS / 64, 256, 0, stream>>>(h2_bf, W3T, b3, att, gamma, beta, out);
}

// Round 7
// 116.584 us; speedup vs baseline: 17.6509x; 1.9741x over previous
//
#include <hip/hip_runtime.h>
#include <hip/hip_bf16.h>

#define S_LEN 1024
#define BATCH 16
#define QD 128
#define NH 8
#define HD 32
#define FF 512
#define NROWS (BATCH * S_LEN)  // 16384 token rows
#define EPS 1e-5f

typedef __attribute__((ext_vector_type(4))) float f32x4;
typedef __attribute__((ext_vector_type(8))) short s16x8;
typedef __attribute__((ext_vector_type(4))) short s16x4;

__device__ __forceinline__ ushort f2bfu(float f) {
    union { float f; unsigned u; } v; v.f = f;
    unsigned r = (v.u + 0x7FFFu + ((v.u >> 16) & 1u)) >> 16;  // RNE
    return (ushort)r;
}

__device__ __forceinline__ float exp2_fast(float x) {
#if __has_builtin(__builtin_amdgcn_exp2f)
    return __builtin_amdgcn_exp2f(x);
#else
    float r;
    asm("v_exp_f32 %0, %1" : "=v"(r) : "v"(x));
    return r;
#endif
}

__device__ __forceinline__ unsigned pk_bf16(float a, float b) {
    union { __hip_bfloat162 h; unsigned u; } c;
    c.h = __float22bfloat162_rn(make_float2(a, b));
    return c.u;
}

static __device__ __forceinline__ f32x4 mfma16(s16x4 a, s16x4 b, f32x4 c) {
#if __has_builtin(__builtin_amdgcn_mfma_f32_16x16x16bf16_1k)
    return __builtin_amdgcn_mfma_f32_16x16x16bf16_1k(a, b, c, 0, 0, 0);
#else
    asm volatile("v_mfma_f32_16x16x16_bf16 %0, %1, %2, %0" : "+v"(c) : "v"(a), "v"(b));
    return c;
#endif
}

static __device__ __forceinline__ f32x4 mfma32(s16x8 a, s16x8 b, f32x4 c) {
    return __builtin_amdgcn_mfma_f32_16x16x32_bf16(a, b, c, 0, 0, 0);
}

__device__ __forceinline__ void gl_lds16(const void* g, void* l) {
    __builtin_amdgcn_global_load_lds(
        (const __attribute__((address_space(1))) void*)g,
        (__attribute__((address_space(3))) void*)l, 16, 0, 0);
}

// ---------------------------------------------------------------------------
// Shared GEMM core: 64 tokens x 128 n per block (4 waves, wave = 16 tok).
// LDS-staged double-buffered K-loop, BK=64:
//   A = WT panel [128 n][64 k] 16 KB, B = act [64 tok][64 k] 8 KB per buffer.
// global_load_lds linear dest + inverse-XOR source; ds_read chunk^(row&7).
// MFMA order identical to the direct-global version (bit-identical results).
// ---------------------------------------------------------------------------
template <int K>
__device__ __forceinline__ void gemm_core(
    const ushort* __restrict__ act, const ushort* __restrict__ WTp,
    char* lds, int tok0, f32x4 acc[8]) {
    const int tid = threadIdx.x;
    const int w = tid >> 6, lane = tid & 63;
    const int qi = lane & 15, g = lane >> 4;
    const int r8 = tid >> 3;
    const int csw = (tid & 7) ^ (r8 & 7);
    const int wave_base = w * 1024;
    constexpr int NT = K / 64;

    auto STAGE = [&](int b, int ks) {
        char* buf = lds + b * 24576;
#pragma unroll
        for (int i = 0; i < 4; ++i)
            gl_lds16(WTp + (size_t)(i * 32 + r8) * K + ks + csw * 8,
                     buf + i * 4096 + wave_base);
#pragma unroll
        for (int j = 0; j < 2; ++j)
            gl_lds16(act + (size_t)(tok0 + j * 32 + r8) * K + ks + csw * 8,
                     buf + 16384 + j * 4096 + wave_base);
    };

    STAGE(0, 0);
    int cur = 0;
#pragma unroll 1
    for (int t = 0; t < NT; ++t) {
        if (t < NT - 1) {
            STAGE(cur ^ 1, (t + 1) * 64);
            asm volatile("s_waitcnt vmcnt(6)" ::: "memory");
        } else {
            asm volatile("s_waitcnt vmcnt(0)" ::: "memory");
        }
        __builtin_amdgcn_sched_barrier(0);
        __builtin_amdgcn_s_barrier();
        __builtin_amdgcn_sched_barrier(0);
        const char* A = lds + cur * 24576;
        const char* B = A + 16384;
        const int brow = w * 16 + qi;
        __builtin_amdgcn_s_setprio(1);
#pragma unroll
        for (int kk2 = 0; kk2 < 2; ++kk2) {
            s16x8 bfrag = *(const s16x8*)(B + brow * 128 +
                                          (((kk2 * 4 + g) ^ (brow & 7)) * 16));
#pragma unroll
            for (int f = 0; f < 8; ++f) {
                const int row = qi + 16 * f;
                s16x8 afrag = *(const s16x8*)(A + row * 128 +
                                              (((kk2 * 4 + g) ^ (row & 7)) * 16));
                acc[f] = mfma32(afrag, bfrag, acc[f]);
            }
        }
        __builtin_amdgcn_s_setprio(0);
        __builtin_amdgcn_sched_barrier(0);
        __builtin_amdgcn_s_barrier();
        __builtin_amdgcn_sched_barrier(0);
        cur ^= 1;
    }
}

// ---------------------------------------------------------------------------
// Kernel 0: weight prep — bf16 transposed copies.
// WoT 128x256 | W1T 512x128 | W2T 512x512 | W3T 128x512 | WqkvT 768x128
// ---------------------------------------------------------------------------
__global__ __launch_bounds__(256) void prep_weights(
    const float* __restrict__ Wo, const float* __restrict__ W1,
    const float* __restrict__ W2, const float* __restrict__ W3,
    const float* __restrict__ Wq, const float* __restrict__ Wk,
    const float* __restrict__ Wv,
    ushort* __restrict__ WoT, ushort* __restrict__ W1T,
    ushort* __restrict__ W2T, ushort* __restrict__ W3T,
    ushort* __restrict__ WqkvT) {
    int idx = blockIdx.x * 256 + threadIdx.x;
    if (idx < 32768) {
        int n = idx >> 8, k = idx & 255;
        WoT[n * 256 + k] = f2bfu(Wo[k * 128 + n]);
    } else if (idx < 98304) {
        int i = idx - 32768; int n = i >> 7, k = i & 127;
        W1T[n * 128 + k] = f2bfu(W1[k * 512 + n]);
    } else if (idx < 360448) {
        int i = idx - 98304; int n = i >> 9, k = i & 511;
        W2T[n * 512 + k] = f2bfu(W2[k * 512 + n]);
    } else if (idx < 425984) {
        int i = idx - 360448; int n = i >> 9, k = i & 511;
        W3T[n * 512 + k] = f2bfu(W3[k * 128 + n]);
    } else {
        int i = idx - 425984;            // 0..98303
        int n = i >> 7, k = i & 127;     // n = p*256 + h*32 + d
        int p = n >> 8, h = (n >> 5) & 7, d = n & 31;
        const float* W = (p == 0) ? Wq : (p == 1) ? Wk : Wv;
        WqkvT[n * 128 + k] = f2bfu(W[(h * QD + k) * HD + d]);
    }
}

// ---------------------------------------------------------------------------
// Kernel 1a: seq f32 [S,B,128] -> x_bf bf16 token-major [b*1024+s][128]
// ---------------------------------------------------------------------------
__global__ __launch_bounds__(256) void seq2bf(
    const float* __restrict__ seq, ushort* __restrict__ x_bf) {
    int t = blockIdx.x * 256 + threadIdx.x;
    int e4 = t * 4;
    int s = e4 >> 11, b = (e4 >> 7) & 15, c = e4 & 127;
    float4 v = *(const float4*)(seq + e4);
    ushort4 o = {f2bfu(v.x), f2bfu(v.y), f2bfu(v.z), f2bfu(v.w)};
    *(ushort4*)(x_bf + ((size_t)(b * 1024 + s)) * 128 + c) = o;
}

// ---------------------------------------------------------------------------
// Kernel 1b: qkv_mfma — LDS-staged GEMM [16384 x 768 x 128].
// ---------------------------------------------------------------------------
__global__ __launch_bounds__(256) void qkv_mfma(
    const ushort* __restrict__ x_bf, const ushort* __restrict__ WqkvT,
    const float* __restrict__ bq, const float* __restrict__ bk,
    const float* __restrict__ bv,
    ushort* __restrict__ q_bf, ushort* __restrict__ k_bf,
    ushort* __restrict__ vT) {
    __shared__ __align__(16) char lds[2 * 24576];
    const int lane = threadIdx.x & 63;
    const int w = threadIdx.x >> 6;
    const int qi = lane & 15, g = lane >> 4;
    const int tok0 = blockIdx.x * 64;
    const int tok = tok0 + w * 16 + qi;
    const int n0 = blockIdx.y * 128;

    f32x4 acc[8];
#pragma unroll
    for (int f = 0; f < 8; ++f) acc[f] = (f32x4){0.f, 0.f, 0.f, 0.f};
    gemm_core<128>(x_bf, WqkvT + (size_t)n0 * 128, lds, tok0, acc);

    const int b = tok >> 10, s = tok & 1023;
    const float SCALE = 0.25503491f;  // log2(e)/sqrt(32)
    if (n0 < 256) {
#pragma unroll
        for (int f = 0; f < 8; ++f)
#pragma unroll
            for (int r = 0; r < 4; ++r) {
                int n = n0 + 16 * f + 4 * g + r;
                int h = (n >> 5) & 7, d = n & 31;
                q_bf[((size_t)(b * 8 + h) * 1024 + s) * 32 + d] =
                    f2bfu((acc[f][r] + bq[h * 32 + d]) * SCALE);
            }
    } else if (n0 < 512) {
#pragma unroll
        for (int f = 0; f < 8; ++f)
#pragma unroll
            for (int r = 0; r < 4; ++r) {
                int n = n0 + 16 * f + 4 * g + r;
                int h = (n >> 5) & 7, d = n & 31;
                k_bf[((size_t)(b * 8 + h) * 1024 + s) * 32 + d] =
                    f2bfu(acc[f][r] + bk[h * 32 + d]);
            }
    } else {
#pragma unroll
        for (int f = 0; f < 8; ++f)
#pragma unroll
            for (int r = 0; r < 4; ++r) {
                int n = n0 + 16 * f + 4 * g + r;
                int h = (n >> 5) & 7, d = n & 31;
                vT[((size_t)(b * 8 + h) * 32 + d) * 1024 + s] =
                    f2bfu(acc[f][r] + bv[h * 32 + d]);
            }
    }
}

// ---------------------------------------------------------------------------
// Kernel 2: flash-style MFMA attention with LDS-staged K/V shared by 4 waves.
// ---------------------------------------------------------------------------
__global__ __launch_bounds__(256) void attn_mfma(
    const ushort* __restrict__ qb, const ushort* __restrict__ kb,
    const ushort* __restrict__ vtb, ushort* __restrict__ o_bf) {
    __shared__ __align__(16) char lds[2][8192];  // [buf][K 4KB | V 4KB]
    const int tid = threadIdx.x;
    const int w = tid >> 6, lane = tid & 63;
    const int g = lane >> 4, qi = lane & 15;
    const int bid = blockIdx.x;
    const int swz = (bid & 7) * 256 + (bid >> 3);
    const int bh = swz >> 4;
    const int qtile = (swz & 15) * 4 + w;

    const ushort* Kb = kb + (size_t)bh * S_LEN * HD;
    const ushort* VTb = vtb + (size_t)bh * HD * S_LEN;
    const s16x8 qf = *(const s16x8*)(qb + ((size_t)bh * S_LEN + qtile * 16 + qi) * HD + g * 8);

    const int krow = tid >> 2;
    const int ksw = (tid & 3) ^ ((tid >> 3) & 3);
    const int vrow = tid >> 3;
    const int vsw = (tid & 7) ^ ((tid >> 4) & 7);
    const int wave_off = w * 1024;

#define STAGE(bufp, k0)                                                          \
    do {                                                                         \
        gl_lds16(Kb + (size_t)((k0) + krow) * HD + ksw * 8, (bufp) + wave_off);  \
        gl_lds16(VTb + (size_t)vrow * S_LEN + (k0) + vsw * 8,                    \
                 (bufp) + 4096 + wave_off);                                      \
    } while (0)

    f32x4 ot0 = {0.f, 0.f, 0.f, 0.f};
    f32x4 ot1 = {0.f, 0.f, 0.f, 0.f};
    float m_run = -1e30f, l_run = 0.f;
    const f32x4 zero = {0.f, 0.f, 0.f, 0.f};

    const int koff = (g ^ ((qi >> 1) & 3)) * 16;
    const int vs = (qi >> 1) & 7;

    STAGE(lds[0], 0);
    int cur = 0;
#pragma unroll 1
    for (int t = 0; t < 16; ++t) {
        if (t < 15) {
            STAGE(lds[cur ^ 1], (t + 1) * 64);
            asm volatile("s_waitcnt vmcnt(2)" ::: "memory");
        } else {
            asm volatile("s_waitcnt vmcnt(0)" ::: "memory");
        }
        __builtin_amdgcn_sched_barrier(0);
        __builtin_amdgcn_s_barrier();
        __builtin_amdgcn_sched_barrier(0);

        const char* kl = lds[cur];
        const char* vl = lds[cur] + 4096;
        s16x8 ka[4];
#pragma unroll
        for (int kt = 0; kt < 4; ++kt)
            ka[kt] = *(const s16x8*)(kl + (16 * kt + qi) * 64 + koff);
        s16x4 va[2][4];
#pragma unroll
        for (int h = 0; h < 2; ++h)
#pragma unroll
            for (int kt = 0; kt < 4; ++kt) {
                int c8 = 4 * kt + g;
                va[h][kt] = *(const s16x4*)(vl + (16 * h + qi) * 128 +
                                            (((c8 >> 1) ^ vs) * 16) + (c8 & 1) * 8);
            }

        f32x4 st[4];
        __builtin_amdgcn_s_setprio(1);
#pragma unroll
        for (int kt = 0; kt < 4; ++kt) st[kt] = mfma32(ka[kt], qf, zero);
        __builtin_amdgcn_s_setprio(0);

        float a0 = fmaxf(fmaxf(st[0][0], st[0][1]), fmaxf(st[0][2], st[0][3]));
        float a1 = fmaxf(fmaxf(st[1][0], st[1][1]), fmaxf(st[1][2], st[1][3]));
        float a2 = fmaxf(fmaxf(st[2][0], st[2][1]), fmaxf(st[2][2], st[2][3]));
        float a3 = fmaxf(fmaxf(st[3][0], st[3][1]), fmaxf(st[3][2], st[3][3]));
        float pmax = fmaxf(fmaxf(a0, a1), fmaxf(a2, a3));

        if (!__all(pmax <= m_run + 8.0f)) {  // defer-max (log2 units)
            float mt = pmax;
            mt = fmaxf(mt, __shfl_xor(mt, 16, 64));
            mt = fmaxf(mt, __shfl_xor(mt, 32, 64));
            float m_new = fmaxf(m_run, mt);
            float alpha = exp2_fast(m_run - m_new);
            l_run *= alpha;
#pragma unroll
            for (int r = 0; r < 4; ++r) { ot0[r] *= alpha; ot1[r] *= alpha; }
            m_run = m_new;
        }

        float p[4][4];
#pragma unroll
        for (int kt = 0; kt < 4; ++kt)
#pragma unroll
            for (int r = 0; r < 4; ++r) p[kt][r] = exp2_fast(st[kt][r] - m_run);
        float s0 = (p[0][0] + p[0][1]) + (p[0][2] + p[0][3]);
        float s1 = (p[1][0] + p[1][1]) + (p[1][2] + p[1][3]);
        float s2 = (p[2][0] + p[2][1]) + (p[2][2] + p[2][3]);
        float s3 = (p[3][0] + p[3][1]) + (p[3][2] + p[3][3]);
        l_run += (s0 + s1) + (s2 + s3);

        union { s16x4 v; uint2 u; } pb[4];
#pragma unroll
        for (int kt = 0; kt < 4; ++kt) {
            pb[kt].u.x = pk_bf16(p[kt][0], p[kt][1]);
            pb[kt].u.y = pk_bf16(p[kt][2], p[kt][3]);
        }
        __builtin_amdgcn_s_setprio(1);
#pragma unroll
        for (int kt = 0; kt < 4; ++kt) {
            ot0 = mfma16(va[0][kt], pb[kt].v, ot0);
            ot1 = mfma16(va[1][kt], pb[kt].v, ot1);
        }
        __builtin_amdgcn_s_setprio(0);

        __builtin_amdgcn_sched_barrier(0);
        __builtin_amdgcn_s_barrier();
        __builtin_amdgcn_sched_barrier(0);
        cur ^= 1;
    }
#undef STAGE

    l_run += __shfl_xor(l_run, 16, 64);
    l_run += __shfl_xor(l_run, 32, 64);
    const float inv_l = 1.0f / l_run;
    const int b = bh >> 3, head = bh & 7;
    const int qg = qtile * 16 + qi;
    ushort* orow = o_bf + ((size_t)(b * S_LEN + qg)) * (NH * HD) + head * HD;
    ushort4 ob0 = {f2bfu(ot0[0] * inv_l), f2bfu(ot0[1] * inv_l),
                   f2bfu(ot0[2] * inv_l), f2bfu(ot0[3] * inv_l)};
    ushort4 ob1 = {f2bfu(ot1[0] * inv_l), f2bfu(ot1[1] * inv_l),
                   f2bfu(ot1[2] * inv_l), f2bfu(ot1[3] * inv_l)};
    *(ushort4*)(orow + g * 4) = ob0;
    *(ushort4*)(orow + 16 + g * 4) = ob1;
}

// ---------------------------------------------------------------------------
// Kernel 3: wo_ln_mfma — att = LN(x + o @ Wo + bo); emits f32 + bf16 copies.
// ---------------------------------------------------------------------------
__global__ __launch_bounds__(256) void wo_ln_mfma(
    const ushort* __restrict__ o_bf, const ushort* __restrict__ WoT,
    const float* __restrict__ bo, const float* __restrict__ seq,
    const float* __restrict__ gamma, const float* __restrict__ beta,
    float* __restrict__ att, ushort* __restrict__ att_bf) {
    __shared__ __align__(16) char lds[2 * 24576];
    const int lane = threadIdx.x & 63;
    const int w = threadIdx.x >> 6;
    const int qi = lane & 15, g = lane >> 4;
    const int tok0 = blockIdx.x * 64;
    const int tok = tok0 + w * 16 + qi;

    f32x4 acc[8];
#pragma unroll
    for (int f = 0; f < 8; ++f) acc[f] = (f32x4){0.f, 0.f, 0.f, 0.f};
    gemm_core<256>(o_bf, WoT, lds, tok0, acc);

    const int b = tok >> 10, s = tok & 1023;
    const float* xrow = seq + (size_t)(s * BATCH + b) * QD;
    float sum = 0.f, sumsq = 0.f;
#pragma unroll
    for (int f = 0; f < 8; ++f) {
        const int c = 16 * f + 4 * g;
        float4 bv = *(const float4*)(bo + c);
        float4 xv = *(const float4*)(xrow + c);
        acc[f][0] += bv.x + xv.x;
        acc[f][1] += bv.y + xv.y;
        acc[f][2] += bv.z + xv.z;
        acc[f][3] += bv.w + xv.w;
#pragma unroll
        for (int r = 0; r < 4; ++r) { sum += acc[f][r]; sumsq += acc[f][r] * acc[f][r]; }
    }
    sum += __shfl_xor(sum, 16, 64);
    sum += __shfl_xor(sum, 32, 64);
    sumsq += __shfl_xor(sumsq, 16, 64);
    sumsq += __shfl_xor(sumsq, 32, 64);
    const float mu = sum * (1.0f / QD);
    const float var = sumsq * (1.0f / QD) - mu * mu;
    const float rstd = rsqrtf(var + EPS);

#pragma unroll
    for (int f = 0; f < 8; ++f) {
        const int c = 16 * f + 4 * g;
        float4 gm = *(const float4*)(gamma + c);
        float4 bt = *(const float4*)(beta + c);
        float4 ov;
        ov.x = (acc[f][0] - mu) * rstd * gm.x + bt.x;
        ov.y = (acc[f][1] - mu) * rstd * gm.y + bt.y;
        ov.z = (acc[f][2] - mu) * rstd * gm.z + bt.z;
        ov.w = (acc[f][3] - mu) * rstd * gm.w + bt.w;
        *(float4*)(att + (size_t)tok * QD + c) = ov;
        ushort4 pv = {f2bfu(ov.x), f2bfu(ov.y), f2bfu(ov.z), f2bfu(ov.w)};
        *(ushort4*)(att_bf + (size_t)tok * QD + c) = pv;
    }
}

// ---------------------------------------------------------------------------
// Kernel 4/5: ffn_mfma — out_bf = relu(act_bf @ WT^T + bias).
// ---------------------------------------------------------------------------
template <int K>
__global__ __launch_bounds__(256) void ffn_mfma(
    const ushort* __restrict__ act, const ushort* __restrict__ WT,
    const float* __restrict__ bias, ushort* __restrict__ out, int N) {
    __shared__ __align__(16) char lds[2 * 24576];
    const int lane = threadIdx.x & 63;
    const int w = threadIdx.x >> 6;
    const int qi = lane & 15, g = lane >> 4;
    const int tok0 = blockIdx.x * 64;
    const int tok = tok0 + w * 16 + qi;
    const int n0 = blockIdx.y * 128;

    f32x4 acc[8];
#pragma unroll
    for (int f = 0; f < 8; ++f) acc[f] = (f32x4){0.f, 0.f, 0.f, 0.f};
    gemm_core<K>(act, WT + (size_t)n0 * K, lds, tok0, acc);

#pragma unroll
    for (int f = 0; f < 8; ++f) {
        const int c = n0 + 16 * f + 4 * g;
        float4 bv = *(const float4*)(bias + c);
        ushort4 pv;
        pv.x = f2bfu(fmaxf(acc[f][0] + bv.x, 0.f));
        pv.y = f2bfu(fmaxf(acc[f][1] + bv.y, 0.f));
        pv.z = f2bfu(fmaxf(acc[f][2] + bv.z, 0.f));
        pv.w = f2bfu(fmaxf(acc[f][3] + bv.w, 0.f));
        *(ushort4*)(out + (size_t)tok * N + c) = pv;
    }
}

// ---------------------------------------------------------------------------
// Kernel 6: w3_ln_mfma — out = LN(att + h2 @ W3 + b3), written to [S,B,128] f32.
// ---------------------------------------------------------------------------
__global__ __launch_bounds__(256) void w3_ln_mfma(
    const ushort* __restrict__ h2, const ushort* __restrict__ W3T,
    const float* __restrict__ b3, const float* __restrict__ att,
    const float* __restrict__ gamma, const float* __restrict__ beta,
    float* __restrict__ out) {
    __shared__ __align__(16) char lds[2 * 24576];
    const int lane = threadIdx.x & 63;
    const int w = threadIdx.x >> 6;
    const int qi = lane & 15, g = lane >> 4;
    const int tok0 = blockIdx.x * 64;
    const int tok = tok0 + w * 16 + qi;

    f32x4 acc[8];
#pragma unroll
    for (int f = 0; f < 8; ++f) acc[f] = (f32x4){0.f, 0.f, 0.f, 0.f};
    gemm_core<512>(h2, W3T, lds, tok0, acc);

    float sum = 0.f, sumsq = 0.f;
#pragma unroll
    for (int f = 0; f < 8; ++f) {
        const int c = 16 * f + 4 * g;
        float4 bv = *(const float4*)(b3 + c);
        float4 xv = *(const float4*)(att + (size_t)tok * QD + c);
        acc[f][0] += bv.x + xv.x;
        acc[f][1] += bv.y + xv.y;
        acc[f][2] += bv.z + xv.z;
        acc[f][3] += bv.w + xv.w;
#pragma unroll
        for (int r = 0; r < 4; ++r) { sum += acc[f][r]; sumsq += acc[f][r] * acc[f][r]; }
    }
    sum += __shfl_xor(sum, 16, 64);
    sum += __shfl_xor(sum, 32, 64);
    sumsq += __shfl_xor(sumsq, 16, 64);
    sumsq += __shfl_xor(sumsq, 32, 64);
    const float mu = sum * (1.0f / QD);
    const float var = sumsq * (1.0f / QD) - mu * mu;
    const float rstd = rsqrtf(var + EPS);

    const int b = tok >> 10, s = tok & 1023;
    float* orow = out + (size_t)(s * BATCH + b) * QD;
#pragma unroll
    for (int f = 0; f < 8; ++f) {
        const int c = 16 * f + 4 * g;
        float4 gm = *(const float4*)(gamma + c);
        float4 bt = *(const float4*)(beta + c);
        float4 ov;
        ov.x = (acc[f][0] - mu) * rstd * gm.x + bt.x;
        ov.y = (acc[f][1] - mu) * rstd * gm.y + bt.y;
        ov.z = (acc[f][2] - mu) * rstd * gm.z + bt.z;
        ov.w = (acc[f][3] - mu) * rstd * gm.w + bt.w;
        *(float4*)(orow + c) = ov;
    }
}

extern "C" void kernel_launch(void* const* d_in, const int* in_sizes, int n_in,
                              void* d_out, int out_size, void* d_ws, size_t ws_size,
                              hipStream_t stream) {
    const float* seq = (const float*)d_in[0];
    const float* Wq = (const float*)d_in[1];
    const float* bq = (const float*)d_in[2];
    const float* Wk = (const float*)d_in[3];
    const float* bk = (const float*)d_in[4];
    const float* Wv = (const float*)d_in[5];
    const float* bv = (const float*)d_in[6];
    const float* Wo = (const float*)d_in[7];
    const float* bo = (const float*)d_in[8];
    const float* gamma = (const float*)d_in[9];
    const float* beta = (const float*)d_in[10];
    const float* W1 = (const float*)d_in[11];
    const float* b1 = (const float*)d_in[12];
    const float* W2 = (const float*)d_in[13];
    const float* b2 = (const float*)d_in[14];
    const float* W3 = (const float*)d_in[15];
    const float* b3 = (const float*)d_in[16];

    char* wsb = (char*)d_ws;
    ushort* q_bf  = (ushort*)(wsb);                    // [0, 8 MB)
    ushort* k_bf  = (ushort*)(wsb + (8ull << 20));     // [8, 16)
    ushort* vT    = (ushort*)(wsb + (16ull << 20));    // [16, 24)
    ushort* o_bf  = (ushort*)(wsb + (24ull << 20));    // [24, 32)
    float*  att   = (float*)(wsb + (32ull << 20));     // [32, 40)
    ushort* att_bf= (ushort*)(wsb + (40ull << 20));    // [40, 44)
    ushort* h1_bf = (ushort*)(wsb);                    // [0, 16) after attn
    ushort* h2_bf = (ushort*)(wsb + (16ull << 20));    // [16, 32) after wo_ln
    ushort* x_bf  = (ushort*)(wsb + (45ull << 20));    // [45, 49) 4 MB
    ushort* WoT   = (ushort*)(wsb + (49ull << 20));
    ushort* W1T   = WoT + 32768;
    ushort* W2T   = W1T + 65536;
    ushort* W3T   = W2T + 262144;
    ushort* WqkvT = W3T + 65536;                       // 768*128
    float* out = (float*)d_out;

    prep_weights<<<2048, 256, 0, stream>>>(Wo, W1, W2, W3, Wq, Wk, Wv,
                                           WoT, W1T, W2T, W3T, WqkvT);
    seq2bf<<<2048, 256, 0, stream>>>(seq, x_bf);
    qkv_mfma<<<dim3(NROWS / 64, 6), 256, 0, stream>>>(x_bf, WqkvT, bq, bk, bv,
                                                      q_bf, k_bf, vT);
    attn_mfma<<<(BATCH * NH) * 16, 256, 0, stream>>>(q_bf, k_bf, vT, o_bf);
    wo_ln_mfma<<<NROWS / 64, 256, 0, stream>>>(o_bf, WoT, bo, seq, gamma, beta, att, att_bf);
    ffn_mfma<QD><<<dim3(NROWS / 64, 4), 256, 0, stream>>>(att_bf, W1T, b1, h1_bf, FF);
    ffn_mfma<FF><<<dim3(NROWS / 64, 4), 256, 0, stream>>>(h1_bf, W2T, b2, h2_bf, FF);
    w3_ln_mfma<<<NROWS / 64, 256, 0, stream>>>(h2_bf, W3T, b3, att, gamma, beta, out);
}